// Round 1
// baseline (13686.299 us; speedup 1.0000x reference)
//
#include <hip/hip_runtime.h>
#include <hip/hip_bf16.h>
#include <math.h>

#define B_  2
#define N_  1024
#define E_  768
#define H_  12
#define HD_ 64
#define L_  6
#define FF_ 3072
#define V_  50257

__device__ __forceinline__ float gelu_f(float x) {
  // tanh-approximation GELU, matches reference
  return 0.5f * x * (1.0f + tanhf(0.7978845608028654f * (x + 0.044715f * x * x * x)));
}

// h[b,n,e] = tok_emb[x[b,n], e] + sinusoidal_pos(n, e)
// pos emb: exponent 2*e/dim for BOTH even (sin) and odd (cos) indices
__global__ __launch_bounds__(256) void embed_kernel(const int* __restrict__ x,
    const float* __restrict__ tok, float* __restrict__ h) {
  int idx = blockIdx.x * 256 + threadIdx.x;
  const int total = B_ * N_ * E_;
  if (idx >= total) return;
  int e  = idx % E_;
  int bn = idx / E_;
  int n  = bn % N_;
  int t  = x[bn];
  // 1/10000^(2e/768) = exp(-ln(10000)*2e/768)
  float freq = expf(-9.210340371976184f * (float)(2 * e) / (float)E_);
  float arg  = (float)n * freq;
  float pe   = (e & 1) ? cosf(arg) : sinf(arg);
  h[idx] = tok[(size_t)t * E_ + e] + pe;
}

// one block per row of 768; biased variance; eps 1e-5
__global__ __launch_bounds__(256) void layernorm_kernel(const float* __restrict__ in,
    float* __restrict__ out, const float* __restrict__ g, const float* __restrict__ b) {
  int row = blockIdx.x;
  const float* xr = in + (size_t)row * E_;
  __shared__ float red[256];
  int tid = threadIdx.x;
  float s = 0.f, ss = 0.f;
  for (int e = tid; e < E_; e += 256) { float v = xr[e]; s += v; ss += v * v; }
  red[tid] = s; __syncthreads();
  for (int o = 128; o > 0; o >>= 1) { if (tid < o) red[tid] += red[tid + o]; __syncthreads(); }
  float mean = red[0] / (float)E_;
  __syncthreads();
  red[tid] = ss; __syncthreads();
  for (int o = 128; o > 0; o >>= 1) { if (tid < o) red[tid] += red[tid + o]; __syncthreads(); }
  float var = red[0] / (float)E_ - mean * mean;
  float inv = rsqrtf(var + 1e-5f);
  for (int e = tid; e < E_; e += 256)
    out[(size_t)row * E_ + e] = g[e] * (xr[e] - mean) * inv + b[e];
}

// C[M,Nn] = A[M,K] @ B[K,Nn] (+bias over Nn) (+optional GELU)
// 64x64 C-tile, BK=16, 256 threads, 4x4 micro-tile per thread.
// M % 64 == 0 and K % 16 == 0 always hold here; Nn may be ragged (50257).
__global__ __launch_bounds__(256) void gemm_kernel(const float* __restrict__ A,
    const float* __restrict__ Bm, const float* __restrict__ bias,
    float* __restrict__ C, int M, int Nn, int K, int act) {
  __shared__ float As[16][65];  // [kk][m]
  __shared__ float Bs[16][65];  // [kk][n]
  int tid  = threadIdx.x;
  int row0 = blockIdx.y * 64;
  int col0 = blockIdx.x * 64;
  int tx = tid & 15, ty = tid >> 4;
  float acc[4][4] = {};
  for (int k0 = 0; k0 < K; k0 += 16) {
#pragma unroll
    for (int t = 0; t < 4; ++t) {          // A tile: 64x16, 4 consecutive K per thread
      int e = tid * 4 + t;
      int m = e >> 4, kk = e & 15;
      As[kk][m] = A[(size_t)(row0 + m) * K + (k0 + kk)];
    }
#pragma unroll
    for (int t = 0; t < 4; ++t) {          // B tile: 16x64, coalesced along Nn
      int e = tid * 4 + t;
      int kk = e >> 6, nc = e & 63;
      int col = col0 + nc;
      Bs[kk][nc] = (col < Nn) ? Bm[(size_t)(k0 + kk) * Nn + col] : 0.0f;
    }
    __syncthreads();
#pragma unroll
    for (int kk = 0; kk < 16; ++kk) {
      float a[4], b[4];
#pragma unroll
      for (int i = 0; i < 4; ++i) a[i] = As[kk][ty * 4 + i];
#pragma unroll
      for (int j = 0; j < 4; ++j) b[j] = Bs[kk][tx * 4 + j];
#pragma unroll
      for (int i = 0; i < 4; ++i)
#pragma unroll
        for (int j = 0; j < 4; ++j)
          acc[i][j] += a[i] * b[j];
    }
    __syncthreads();
  }
#pragma unroll
  for (int i = 0; i < 4; ++i) {
    int row = row0 + ty * 4 + i;
#pragma unroll
    for (int j = 0; j < 4; ++j) {
      int col = col0 + tx * 4 + j;
      if (col < Nn) {
        float val = acc[i][j];
        if (bias) val += bias[col];
        if (act == 1) val = gelu_f(val);
        C[(size_t)row * Nn + col] = val;
      }
    }
  }
}

// one block per (query row, head, batch); scores row in LDS; causal softmax; PV.
// q/k/v layout: [b*N+n][E] with head h at cols h*64..h*64+63.
__global__ __launch_bounds__(256) void attn_kernel(const float* __restrict__ q,
    const float* __restrict__ k, const float* __restrict__ v, float* __restrict__ o) {
  int qi = blockIdx.x, hh = blockIdx.y, bz = blockIdx.z;
  __shared__ float s[N_];
  __shared__ float qs[HD_];
  __shared__ float red[256];
  int tid = threadIdx.x;
  const float* qp = q + ((size_t)(bz * N_ + qi)) * E_ + hh * HD_;
  if (tid < HD_) qs[tid] = qp[tid];
  __syncthreads();
  for (int kk = tid; kk < N_; kk += 256) {
    float acc;
    if (kk <= qi) {  // causal: keys strictly after the query are masked
      const float* kp = k + ((size_t)(bz * N_ + kk)) * E_ + hh * HD_;
      acc = 0.f;
      for (int d = 0; d < HD_; ++d) acc += qs[d] * kp[d];
      acc *= 0.125f;  // 1/sqrt(64); mask-before-scale: -inf/8 stays -inf
    } else {
      acc = -INFINITY;
    }
    s[kk] = acc;
  }
  __syncthreads();
  float lm = -INFINITY;
  for (int kk = tid; kk < N_; kk += 256) lm = fmaxf(lm, s[kk]);
  red[tid] = lm; __syncthreads();
  for (int off = 128; off > 0; off >>= 1) { if (tid < off) red[tid] = fmaxf(red[tid], red[tid + off]); __syncthreads(); }
  float mx = red[0];
  __syncthreads();
  float ls = 0.f;
  for (int kk = tid; kk < N_; kk += 256) { float ex = expf(s[kk] - mx); s[kk] = ex; ls += ex; }
  red[tid] = ls; __syncthreads();
  for (int off = 128; off > 0; off >>= 1) { if (tid < off) red[tid] += red[tid + off]; __syncthreads(); }
  float inv = 1.f / red[0];
  __syncthreads();
  // PV: 4 groups of 64 lanes; lane owns output dim d, groups split k range
  int d = tid & 63, grp = tid >> 6;
  float acc = 0.f;
  int kmax = qi + 1;
  for (int kk = grp; kk < kmax; kk += 4)
    acc += s[kk] * v[((size_t)(bz * N_ + kk)) * E_ + hh * HD_ + d];
  red[tid] = acc; __syncthreads();
  if (tid < 64) {
    float r = red[tid] + red[tid + 64] + red[tid + 128] + red[tid + 192];
    o[((size_t)(bz * N_ + qi)) * E_ + hh * HD_ + tid] = r * inv;
  }
}

__global__ __launch_bounds__(256) void add_kernel(float* __restrict__ a,
    const float* __restrict__ b, int n) {
  int i = blockIdx.x * 256 + threadIdx.x;
  if (i < n) a[i] += b[i];
}

extern "C" void kernel_launch(void* const* d_in, const int* in_sizes, int n_in,
                              void* d_out, int out_size, void* d_ws, size_t ws_size,
                              hipStream_t stream) {
  const int*   x     = (const int*)  d_in[0];
  const float* tok   = (const float*)d_in[1];
  const float* wq    = (const float*)d_in[2];
  const float* wk    = (const float*)d_in[3];
  const float* wv    = (const float*)d_in[4];
  const float* wo    = (const float*)d_in[5];
  const float* bo    = (const float*)d_in[6];
  const float* ln1g  = (const float*)d_in[7];
  const float* ln1b  = (const float*)d_in[8];
  const float* ln2g  = (const float*)d_in[9];
  const float* ln2b  = (const float*)d_in[10];
  const float* w1    = (const float*)d_in[11];
  const float* b1    = (const float*)d_in[12];
  const float* w2    = (const float*)d_in[13];
  const float* b2    = (const float*)d_in[14];
  const float* lnfg  = (const float*)d_in[15];
  const float* lnfb  = (const float*)d_in[16];
  const float* whead = (const float*)d_in[17];
  float* out = (float*)d_out;

  const size_t SZ = (size_t)B_ * N_ * E_;       // 1572864 floats
  float* ws  = (float*)d_ws;
  float* h   = ws;
  float* y   = ws + SZ;
  float* q   = ws + 2 * SZ;
  float* k   = ws + 3 * SZ;
  float* v   = ws + 4 * SZ;
  float* o   = ws + 5 * SZ;
  float* mid = ws + 6 * SZ;                      // B*N*FF = 4*SZ more; total 10*SZ (~60 MB)

  dim3 blk(256);
  const int M = B_ * N_;                         // 2048

  embed_kernel<<<(B_ * N_ * E_ + 255) / 256, blk, 0, stream>>>(x, tok, h);

  dim3 g1((E_ + 63) / 64, (M + 63) / 64);        // 768-col GEMMs
  dim3 g2((FF_ + 63) / 64, (M + 63) / 64);       // 3072-col GEMM
  dim3 ga(N_, H_, B_);                           // attention

  for (int l = 0; l < L_; ++l) {
    layernorm_kernel<<<M, blk, 0, stream>>>(h, y, ln1g + (size_t)l * E_, ln1b + (size_t)l * E_);
    gemm_kernel<<<g1, blk, 0, stream>>>(y, wq + (size_t)l * E_ * E_, nullptr, q, M, E_, E_, 0);
    gemm_kernel<<<g1, blk, 0, stream>>>(y, wk + (size_t)l * E_ * E_, nullptr, k, M, E_, E_, 0);
    gemm_kernel<<<g1, blk, 0, stream>>>(y, wv + (size_t)l * E_ * E_, nullptr, v, M, E_, E_, 0);
    attn_kernel<<<ga, blk, 0, stream>>>(q, k, v, o);
    gemm_kernel<<<g1, blk, 0, stream>>>(o, wo + (size_t)l * E_ * E_, bo + (size_t)l * E_, y, M, E_, E_, 0);
    add_kernel<<<(int)((SZ + 255) / 256), blk, 0, stream>>>(h, y, (int)SZ);
    layernorm_kernel<<<M, blk, 0, stream>>>(h, y, ln2g + (size_t)l * E_, ln2b + (size_t)l * E_);
    gemm_kernel<<<g2, blk, 0, stream>>>(y, w1 + (size_t)l * E_ * FF_, b1 + (size_t)l * FF_, mid, M, FF_, E_, 1);
    gemm_kernel<<<g1, blk, 0, stream>>>(mid, w2 + (size_t)l * FF_ * E_, b2 + (size_t)l * E_, y, M, E_, FF_, 0);
    add_kernel<<<(int)((SZ + 255) / 256), blk, 0, stream>>>(h, y, (int)SZ);
  }

  layernorm_kernel<<<M, blk, 0, stream>>>(h, y, lnfg, lnfb);
  dim3 gh((V_ + 63) / 64, (M + 63) / 64);
  gemm_kernel<<<gh, blk, 0, stream>>>(y, whead, nullptr, out, M, V_, E_, 0);
}

// Round 2
// 5128.896 us; speedup vs baseline: 2.6685x; 2.6685x over previous
//
#include <hip/hip_runtime.h>
#include <hip/hip_bf16.h>
#include <math.h>

#define B_  2
#define N_  1024
#define E_  768
#define H_  12
#define HD_ 64
#define L_  6
#define FF_ 3072
#define V_  50257
#define VPAD_ 50304
#define QKVW_ 2304
#define M_  (B_ * N_)   // 2048

typedef short short8 __attribute__((ext_vector_type(8)));
typedef float f32x4 __attribute__((ext_vector_type(4)));
typedef unsigned short ushort8 __attribute__((ext_vector_type(8)));

__device__ __forceinline__ float gelu_f(float x) {
  return 0.5f * x * (1.0f + tanhf(0.7978845608028654f * (x + 0.044715f * x * x * x)));
}

__device__ __forceinline__ float bf2f(unsigned short u) {
  return __uint_as_float((unsigned)u << 16);
}

__device__ __forceinline__ void async_ld16(const void* g, void* l) {
  __builtin_amdgcn_global_load_lds(
      (const __attribute__((address_space(1))) void*)g,
      (__attribute__((address_space(3))) void*)l, 16, 0, 0);
}

// ---------------- embed: h = tok_emb[x] + sinusoidal (fp32) ----------------
__global__ __launch_bounds__(256) void embed_kernel(const int* __restrict__ x,
    const float* __restrict__ tok, float* __restrict__ h) {
  int idx = blockIdx.x * 256 + threadIdx.x;
  const int total = B_ * N_ * E_;
  if (idx >= total) return;
  int e  = idx % E_;
  int bn = idx / E_;
  int n  = bn % N_;
  int t  = x[bn];
  float freq = expf(-9.210340371976184f * (float)(2 * e) / (float)E_);
  float arg  = (float)n * freq;
  float pe   = (e & 1) ? cosf(arg) : sinf(arg);
  h[idx] = tok[(size_t)t * E_ + e] + pe;
}

// ---------------- layernorm: fp32 in -> bf16 out ----------------
__global__ __launch_bounds__(256) void layernorm_kernel(const float* __restrict__ in,
    __hip_bfloat16* __restrict__ out, const float* __restrict__ g, const float* __restrict__ b) {
  int row = blockIdx.x;
  const float* xr = in + (size_t)row * E_;
  __shared__ float red[256];
  int tid = threadIdx.x;
  float s = 0.f, ss = 0.f;
  for (int e = tid; e < E_; e += 256) { float v = xr[e]; s += v; ss += v * v; }
  red[tid] = s; __syncthreads();
  for (int o = 128; o > 0; o >>= 1) { if (tid < o) red[tid] += red[tid + o]; __syncthreads(); }
  float mean = red[0] / (float)E_;
  __syncthreads();
  red[tid] = ss; __syncthreads();
  for (int o = 128; o > 0; o >>= 1) { if (tid < o) red[tid] += red[tid + o]; __syncthreads(); }
  float var = red[0] / (float)E_ - mean * mean;
  float inv = rsqrtf(var + 1e-5f);
  for (int e = tid; e < E_; e += 256)
    out[(size_t)row * E_ + e] = __float2bfloat16(g[e] * (xr[e] - mean) * inv + b[e]);
}

// ---------------- transpose + cast: in[K][Nn] fp32 -> out[Npad][K] bf16 ----------------
// rows of out beyond Nn are written as zero (padding for GEMM staging safety)
__global__ __launch_bounds__(256) void transpose_cast_kernel(const float* __restrict__ in,
    __hip_bfloat16* __restrict__ out, int K, int Nn) {
  __shared__ float t[64][65];
  int k0 = blockIdx.x * 64, n0 = blockIdx.y * 64;
  int tid = threadIdx.x;
  int c = tid & 63, rg = tid >> 6;
#pragma unroll
  for (int i = 0; i < 16; ++i) {
    int r = rg * 16 + i;
    int n = n0 + c;
    t[r][c] = (n < Nn) ? in[(size_t)(k0 + r) * Nn + n] : 0.0f;
  }
  __syncthreads();
#pragma unroll
  for (int i = 0; i < 16; ++i) {
    int ro = rg * 16 + i;
    out[(size_t)(n0 + ro) * K + (k0 + c)] = __float2bfloat16(t[c][ro]);
  }
}

// ---------------- MFMA GEMM: C[M,Nn] = A[M,K] @ Bt[Npad,K]^T ----------------
// m97 structure: 128x128 tile, BK=32, 4 waves (2x2 of 64x64), 4x4 16x16x32 frags,
// global_load_lds width-16 staging, ds_read_b128 fragment loads.
__global__ __launch_bounds__(256) void gemm_bt_kernel(
    const __hip_bfloat16* __restrict__ A, const __hip_bfloat16* __restrict__ Bt,
    const float* __restrict__ bias, const float* __restrict__ R,
    float* __restrict__ Cf, __hip_bfloat16* __restrict__ Cb,
    int Nn, int K, int act) {
  __shared__ __align__(16) unsigned short As[128 * 32];
  __shared__ __align__(16) unsigned short Bs[128 * 32];
  int tid = threadIdx.x;
  int w = tid >> 6, l = tid & 63;
  int wr = w >> 1, wc = w & 1;
  int row0 = blockIdx.y * 128, col0 = blockIdx.x * 128;
  int lr = l & 15, kg = l >> 4;
  const unsigned short* Ag = (const unsigned short*)A;
  const unsigned short* Bg = (const unsigned short*)Bt;
  int srow = l >> 2;           // 0..15 within wave's 16-row stripe
  int scol = (l & 3) * 8;      // bf16 element offset within 32-wide K slice

  f32x4 acc[4][4];
#pragma unroll
  for (int m = 0; m < 4; ++m)
#pragma unroll
    for (int n = 0; n < 4; ++n) acc[m][n] = (f32x4){0.f, 0.f, 0.f, 0.f};

  for (int k0 = 0; k0 < K; k0 += 32) {
#pragma unroll
    for (int i = 0; i < 2; ++i) {
      int rbase = i * 64 + w * 16;
      async_ld16(Ag + (size_t)(row0 + rbase + srow) * K + k0 + scol, &As[rbase * 32]);
      async_ld16(Bg + (size_t)(col0 + rbase + srow) * K + k0 + scol, &Bs[rbase * 32]);
    }
    __syncthreads();
    short8 af[4], bf[4];
#pragma unroll
    for (int m = 0; m < 4; ++m)
      af[m] = *(const short8*)&As[(wr * 64 + m * 16 + lr) * 32 + kg * 8];
#pragma unroll
    for (int n = 0; n < 4; ++n)
      bf[n] = *(const short8*)&Bs[(wc * 64 + n * 16 + lr) * 32 + kg * 8];
#pragma unroll
    for (int m = 0; m < 4; ++m)
#pragma unroll
      for (int n = 0; n < 4; ++n)
        acc[m][n] = __builtin_amdgcn_mfma_f32_16x16x32_bf16(af[m], bf[n], acc[m][n], 0, 0, 0);
    __syncthreads();
  }

#pragma unroll
  for (int n = 0; n < 4; ++n) {
    int col = col0 + wc * 64 + n * 16 + lr;
    if (col >= Nn) continue;
    float bv = bias ? bias[col] : 0.f;
#pragma unroll
    for (int m = 0; m < 4; ++m) {
#pragma unroll
      for (int j = 0; j < 4; ++j) {
        int row = row0 + wr * 64 + m * 16 + kg * 4 + j;
        float val = acc[m][n][j] + bv;
        if (act) val = gelu_f(val);
        if (R) val += R[(size_t)row * Nn + col];
        if (Cf) Cf[(size_t)row * Nn + col] = val;
        if (Cb) Cb[(size_t)row * Nn + col] = __float2bfloat16(val);
      }
    }
  }
}

// ---------------- attention: bf16 qkv [M][2304] -> bf16 o [M][768] ----------------
__global__ __launch_bounds__(256) void attn_kernel(const __hip_bfloat16* __restrict__ qkv,
    __hip_bfloat16* __restrict__ o) {
  int qi = blockIdx.x, hh = blockIdx.y, bz = blockIdx.z;
  __shared__ float s[N_];
  __shared__ float qs[HD_];
  __shared__ float red[256];
  int tid = threadIdx.x;
  const unsigned short* base = (const unsigned short*)qkv;
  const unsigned short* qp = base + (size_t)(bz * N_ + qi) * QKVW_ + hh * HD_;
  if (tid < HD_) qs[tid] = bf2f(qp[tid]);
  __syncthreads();
  for (int kk = tid; kk < N_; kk += 256) {
    float acc;
    if (kk <= qi) {
      const ushort8* kp = (const ushort8*)(base + (size_t)(bz * N_ + kk) * QKVW_ + E_ + hh * HD_);
      acc = 0.f;
#pragma unroll
      for (int u = 0; u < 8; ++u) {
        ushort8 kv = kp[u];
#pragma unroll
        for (int j = 0; j < 8; ++j) acc += qs[u * 8 + j] * bf2f(kv[j]);
      }
      acc *= 0.125f;
    } else {
      acc = -INFINITY;
    }
    s[kk] = acc;
  }
  __syncthreads();
  float lm = -INFINITY;
  for (int kk = tid; kk < N_; kk += 256) lm = fmaxf(lm, s[kk]);
  red[tid] = lm; __syncthreads();
  for (int off = 128; off > 0; off >>= 1) { if (tid < off) red[tid] = fmaxf(red[tid], red[tid + off]); __syncthreads(); }
  float mx = red[0];
  __syncthreads();
  float ls = 0.f;
  for (int kk = tid; kk < N_; kk += 256) { float ex = expf(s[kk] - mx); s[kk] = ex; ls += ex; }
  red[tid] = ls; __syncthreads();
  for (int off = 128; off > 0; off >>= 1) { if (tid < off) red[tid] += red[tid + off]; __syncthreads(); }
  float inv = 1.f / red[0];
  __syncthreads();
  int d = tid & 63, grp = tid >> 6;
  float acc = 0.f;
  int kmax = qi + 1;
  for (int kk = grp; kk < kmax; kk += 4)
    acc += s[kk] * bf2f(base[(size_t)(bz * N_ + kk) * QKVW_ + 2 * E_ + hh * HD_ + d]);
  red[tid] = acc; __syncthreads();
  if (tid < 64) {
    float r = red[tid] + red[tid + 64] + red[tid + 128] + red[tid + 192];
    o[(size_t)(bz * N_ + qi) * E_ + hh * HD_ + tid] = __float2bfloat16(r * inv);
  }
}

extern "C" void kernel_launch(void* const* d_in, const int* in_sizes, int n_in,
                              void* d_out, int out_size, void* d_ws, size_t ws_size,
                              hipStream_t stream) {
  const int*   x     = (const int*)  d_in[0];
  const float* tok   = (const float*)d_in[1];
  const float* wq    = (const float*)d_in[2];
  const float* wk    = (const float*)d_in[3];
  const float* wv    = (const float*)d_in[4];
  const float* wo    = (const float*)d_in[5];
  const float* bo    = (const float*)d_in[6];
  const float* ln1g  = (const float*)d_in[7];
  const float* ln1b  = (const float*)d_in[8];
  const float* ln2g  = (const float*)d_in[9];
  const float* ln2b  = (const float*)d_in[10];
  const float* w1    = (const float*)d_in[11];
  const float* b1    = (const float*)d_in[12];
  const float* w2    = (const float*)d_in[13];
  const float* b2    = (const float*)d_in[14];
  const float* lnfg  = (const float*)d_in[15];
  const float* lnfb  = (const float*)d_in[16];
  const float* whead = (const float*)d_in[17];
  float* out = (float*)d_out;

  char* wsb = (char*)d_ws;
  size_t off = 0;
  auto alloc = [&](size_t bytes) -> void* {
    void* p = wsb + off; off += (bytes + 255) & ~(size_t)255; return p;
  };
  float*           h        = (float*)          alloc((size_t)M_ * E_ * 4);
  __hip_bfloat16*  y_bf     = (__hip_bfloat16*) alloc((size_t)M_ * E_ * 2);
  __hip_bfloat16*  qkv_bf   = (__hip_bfloat16*) alloc((size_t)M_ * QKVW_ * 2);
  __hip_bfloat16*  o_bf     = (__hip_bfloat16*) alloc((size_t)M_ * E_ * 2);
  __hip_bfloat16*  mid_bf   = (__hip_bfloat16*) alloc((size_t)M_ * FF_ * 2);
  __hip_bfloat16*  whead_bt = (__hip_bfloat16*) alloc((size_t)VPAD_ * E_ * 2);
  __hip_bfloat16*  qkvw_bt  = (__hip_bfloat16*) alloc((size_t)QKVW_ * E_ * 2);
  __hip_bfloat16*  wo_bt    = (__hip_bfloat16*) alloc((size_t)E_ * E_ * 2);
  __hip_bfloat16*  w1_bt    = (__hip_bfloat16*) alloc((size_t)FF_ * E_ * 2);
  __hip_bfloat16*  w2_bt    = (__hip_bfloat16*) alloc((size_t)E_ * FF_ * 2);

  dim3 blk(256);

  embed_kernel<<<(B_ * N_ * E_ + 255) / 256, blk, 0, stream>>>(x, tok, h);
  // head weight: [768,50257] -> bf16 [50304,768] (zero-padded rows)
  transpose_cast_kernel<<<dim3(E_ / 64, VPAD_ / 64), blk, 0, stream>>>(whead, whead_bt, E_, V_);

  dim3 gqkv(QKVW_ / 128, M_ / 128);
  dim3 gproj(E_ / 128, M_ / 128);
  dim3 gffn1(FF_ / 128, M_ / 128);
  dim3 ga(N_, H_, B_);

  for (int l = 0; l < L_; ++l) {
    const size_t we = (size_t)l * E_ * E_;
    transpose_cast_kernel<<<dim3(12, 12), blk, 0, stream>>>(wq + we, qkvw_bt, E_, E_);
    transpose_cast_kernel<<<dim3(12, 12), blk, 0, stream>>>(wk + we, qkvw_bt + (size_t)E_ * E_, E_, E_);
    transpose_cast_kernel<<<dim3(12, 12), blk, 0, stream>>>(wv + we, qkvw_bt + (size_t)2 * E_ * E_, E_, E_);
    transpose_cast_kernel<<<dim3(12, 12), blk, 0, stream>>>(wo + we, wo_bt, E_, E_);
    transpose_cast_kernel<<<dim3(12, 48), blk, 0, stream>>>(w1 + (size_t)l * E_ * FF_, w1_bt, E_, FF_);
    transpose_cast_kernel<<<dim3(48, 12), blk, 0, stream>>>(w2 + (size_t)l * FF_ * E_, w2_bt, FF_, E_);

    layernorm_kernel<<<M_, blk, 0, stream>>>(h, y_bf, ln1g + (size_t)l * E_, ln1b + (size_t)l * E_);
    gemm_bt_kernel<<<gqkv, blk, 0, stream>>>(y_bf, qkvw_bt, nullptr, nullptr, nullptr, qkv_bf,
                                             QKVW_, E_, 0);
    attn_kernel<<<ga, blk, 0, stream>>>(qkv_bf, o_bf);
    gemm_bt_kernel<<<gproj, blk, 0, stream>>>(o_bf, wo_bt, bo + (size_t)l * E_, h, h, nullptr,
                                              E_, E_, 0);
    layernorm_kernel<<<M_, blk, 0, stream>>>(h, y_bf, ln2g + (size_t)l * E_, ln2b + (size_t)l * E_);
    gemm_bt_kernel<<<gffn1, blk, 0, stream>>>(y_bf, w1_bt, b1 + (size_t)l * FF_, nullptr, nullptr, mid_bf,
                                              FF_, E_, 1);
    gemm_bt_kernel<<<gproj, blk, 0, stream>>>(mid_bf, w2_bt, b2 + (size_t)l * E_, h, h, nullptr,
                                              E_, FF_, 0);
  }

  layernorm_kernel<<<M_, blk, 0, stream>>>(h, y_bf, lnfg, lnfb);
  gemm_bt_kernel<<<dim3(VPAD_ / 128, M_ / 128), blk, 0, stream>>>(y_bf, whead_bt, nullptr, nullptr, out, nullptr,
                                                                  V_, E_, 0);
}

// Round 3
// 2258.773 us; speedup vs baseline: 6.0592x; 2.2707x over previous
//
#include <hip/hip_runtime.h>
#include <hip/hip_bf16.h>
#include <math.h>

#define B_  2
#define N_  1024
#define E_  768
#define H_  12
#define HD_ 64
#define L_  6
#define FF_ 3072
#define V_  50257
#define VPAD_ 50304
#define QKVW_ 2304
#define M_  (B_ * N_)   // 2048

typedef short short8 __attribute__((ext_vector_type(8)));
typedef float f32x4 __attribute__((ext_vector_type(4)));
typedef unsigned short ushort8 __attribute__((ext_vector_type(8)));

__device__ __forceinline__ float gelu_f(float x) {
  return 0.5f * x * (1.0f + tanhf(0.7978845608028654f * (x + 0.044715f * x * x * x)));
}

__device__ __forceinline__ float bf2f(unsigned short u) {
  return __uint_as_float((unsigned)u << 16);
}

__device__ __forceinline__ unsigned short f2bf(float f) {
  __hip_bfloat16 b = __float2bfloat16(f);
  return *reinterpret_cast<unsigned short*>(&b);
}

__device__ __forceinline__ void async_ld16(const void* g, void* l) {
  __builtin_amdgcn_global_load_lds(
      (const __attribute__((address_space(1))) void*)g,
      (__attribute__((address_space(3))) void*)l, 16, 0, 0);
}

// ---------------- embed: h = tok_emb[x] + sinusoidal (fp32) ----------------
__global__ __launch_bounds__(256) void embed_kernel(const int* __restrict__ x,
    const float* __restrict__ tok, float* __restrict__ h) {
  int idx = blockIdx.x * 256 + threadIdx.x;
  const int total = B_ * N_ * E_;
  if (idx >= total) return;
  int e  = idx % E_;
  int bn = idx / E_;
  int n  = bn % N_;
  int t  = x[bn];
  float freq = expf(-9.210340371976184f * (float)(2 * e) / (float)E_);
  float arg  = (float)n * freq;
  float pe   = (e & 1) ? cosf(arg) : sinf(arg);
  h[idx] = tok[(size_t)t * E_ + e] + pe;
}

// ---------------- layernorm: fp32 in -> bf16 out ----------------
__global__ __launch_bounds__(256) void layernorm_kernel(const float* __restrict__ in,
    __hip_bfloat16* __restrict__ out, const float* __restrict__ g, const float* __restrict__ b) {
  int row = blockIdx.x;
  const float* xr = in + (size_t)row * E_;
  __shared__ float red[256];
  int tid = threadIdx.x;
  float s = 0.f, ss = 0.f;
  for (int e = tid; e < E_; e += 256) { float v = xr[e]; s += v; ss += v * v; }
  red[tid] = s; __syncthreads();
  for (int o = 128; o > 0; o >>= 1) { if (tid < o) red[tid] += red[tid + o]; __syncthreads(); }
  float mean = red[0] / (float)E_;
  __syncthreads();
  red[tid] = ss; __syncthreads();
  for (int o = 128; o > 0; o >>= 1) { if (tid < o) red[tid] += red[tid + o]; __syncthreads(); }
  float var = red[0] / (float)E_ - mean * mean;
  float inv = rsqrtf(var + 1e-5f);
  for (int e = tid; e < E_; e += 256)
    out[(size_t)row * E_ + e] = __float2bfloat16(g[e] * (xr[e] - mean) * inv + b[e]);
}

// ---------------- transpose + cast: in[K][Nn] fp32 -> out[Npad][K] bf16 ----------------
__global__ __launch_bounds__(256) void transpose_cast_kernel(const float* __restrict__ in,
    __hip_bfloat16* __restrict__ out, int K, int Nn) {
  __shared__ float t[64][65];
  int k0 = blockIdx.x * 64, n0 = blockIdx.y * 64;
  int tid = threadIdx.x;
  int c = tid & 63, rg = tid >> 6;
#pragma unroll
  for (int i = 0; i < 16; ++i) {
    int r = rg * 16 + i;
    int n = n0 + c;
    t[r][c] = (n < Nn) ? in[(size_t)(k0 + r) * Nn + n] : 0.0f;
  }
  __syncthreads();
#pragma unroll
  for (int i = 0; i < 16; ++i) {
    int ro = rg * 16 + i;
    out[(size_t)(n0 + ro) * K + (k0 + c)] = __float2bfloat16(t[c][ro]);
  }
}

// ---------------- V transpose: qkv [M][2304] bf16 -> vt [B][H][HD][N] bf16 ----------------
__global__ __launch_bounds__(256) void vtrans_kernel(const __hip_bfloat16* __restrict__ qkv,
    __hip_bfloat16* __restrict__ vt) {
  int n0 = blockIdx.x * 64, hh = blockIdx.y, bz = blockIdx.z;
  __shared__ unsigned short t[64][65];
  int tid = threadIdx.x;
  int c = tid & 63, rg = tid >> 6;
  const unsigned short* base = (const unsigned short*)qkv;
#pragma unroll
  for (int i = 0; i < 16; ++i) {
    int n = rg * 16 + i;
    t[n][c] = base[(size_t)(bz * N_ + n0 + n) * QKVW_ + 2 * E_ + hh * HD_ + c];
  }
  __syncthreads();
  unsigned short* vout = (unsigned short*)vt + ((size_t)(bz * H_ + hh)) * HD_ * N_;
#pragma unroll
  for (int i = 0; i < 16; ++i) {
    int d = rg * 16 + i;
    vout[(size_t)d * N_ + n0 + c] = t[c][d];
  }
}

// ---------------- MFMA GEMM: C[M,Nn] = A[M,K] @ Bt[Npad,K]^T ----------------
__global__ __launch_bounds__(256) void gemm_bt_kernel(
    const __hip_bfloat16* __restrict__ A, const __hip_bfloat16* __restrict__ Bt,
    const float* __restrict__ bias, const float* __restrict__ R,
    float* __restrict__ Cf, __hip_bfloat16* __restrict__ Cb,
    int Nn, int K, int act) {
  __shared__ __align__(16) unsigned short As[128 * 32];
  __shared__ __align__(16) unsigned short Bs[128 * 32];
  int tid = threadIdx.x;
  int w = tid >> 6, l = tid & 63;
  int wr = w >> 1, wc = w & 1;
  int row0 = blockIdx.y * 128, col0 = blockIdx.x * 128;
  int lr = l & 15, kg = l >> 4;
  const unsigned short* Ag = (const unsigned short*)A;
  const unsigned short* Bg = (const unsigned short*)Bt;
  int srow = l >> 2;
  int scol = (l & 3) * 8;

  f32x4 acc[4][4];
#pragma unroll
  for (int m = 0; m < 4; ++m)
#pragma unroll
    for (int n = 0; n < 4; ++n) acc[m][n] = (f32x4){0.f, 0.f, 0.f, 0.f};

  for (int k0 = 0; k0 < K; k0 += 32) {
#pragma unroll
    for (int i = 0; i < 2; ++i) {
      int rbase = i * 64 + w * 16;
      async_ld16(Ag + (size_t)(row0 + rbase + srow) * K + k0 + scol, &As[rbase * 32]);
      async_ld16(Bg + (size_t)(col0 + rbase + srow) * K + k0 + scol, &Bs[rbase * 32]);
    }
    __syncthreads();
    short8 af[4], bf[4];
#pragma unroll
    for (int m = 0; m < 4; ++m)
      af[m] = *(const short8*)&As[(wr * 64 + m * 16 + lr) * 32 + kg * 8];
#pragma unroll
    for (int n = 0; n < 4; ++n)
      bf[n] = *(const short8*)&Bs[(wc * 64 + n * 16 + lr) * 32 + kg * 8];
#pragma unroll
    for (int m = 0; m < 4; ++m)
#pragma unroll
      for (int n = 0; n < 4; ++n)
        acc[m][n] = __builtin_amdgcn_mfma_f32_16x16x32_bf16(af[m], bf[n], acc[m][n], 0, 0, 0);
    __syncthreads();
  }

#pragma unroll
  for (int n = 0; n < 4; ++n) {
    int col = col0 + wc * 64 + n * 16 + lr;
    if (col >= Nn) continue;
    float bv = bias ? bias[col] : 0.f;
#pragma unroll
    for (int m = 0; m < 4; ++m) {
#pragma unroll
      for (int j = 0; j < 4; ++j) {
        int row = row0 + wr * 64 + m * 16 + kg * 4 + j;
        float val = acc[m][n][j] + bv;
        if (act) val = gelu_f(val);
        if (R) val += R[(size_t)row * Nn + col];
        if (Cf) Cf[(size_t)row * Nn + col] = val;
        if (Cb) Cb[(size_t)row * Nn + col] = __float2bfloat16(val);
      }
    }
  }
}

// ---------------- flash attention: 1 wave/block, 16 q-rows, 32-key steps ----------------
// qkv [M][2304] bf16, vt [B][H][HD][N] bf16 -> o [M][768] bf16
#define PRS_ 40   // P LDS row stride (shorts): 80B rows, 16B-aligned frag reads
__global__ __launch_bounds__(64) void fattn_kernel(
    const __hip_bfloat16* __restrict__ qkv, const __hip_bfloat16* __restrict__ vt,
    __hip_bfloat16* __restrict__ o) {
  int qt = blockIdx.x, hh = blockIdx.y, bz = blockIdx.z;
  int q0 = qt * 16;
  int l = threadIdx.x;
  int lr = l & 15, kg = l >> 4;
  const unsigned short* base = (const unsigned short*)qkv;
  const unsigned short* vtb = (const unsigned short*)vt + ((size_t)(bz * H_ + hh)) * HD_ * N_;
  __shared__ __align__(16) unsigned short P[16 * PRS_];

  // Q fragments: lane (kg,lr) holds Q[q0+lr][c*32 + kg*8 .. +7]
  short8 qf[2];
  const unsigned short* qrow = base + (size_t)(bz * N_ + q0 + lr) * QKVW_ + hh * HD_;
#pragma unroll
  for (int c = 0; c < 2; ++c) qf[c] = *(const short8*)(qrow + c * 32 + kg * 8);

  float mrow[4], lsum[4];
  f32x4 accO[4];
#pragma unroll
  for (int j = 0; j < 4; ++j) { mrow[j] = -INFINITY; lsum[j] = 0.f; }
#pragma unroll
  for (int db = 0; db < 4; ++db) accO[db] = (f32x4){0.f, 0.f, 0.f, 0.f};

  int nsteps = (q0 + 16 + 31) / 32;   // 32*nsteps <= N always
  for (int kt = 0; kt < nsteps; ++kt) {
    // S tiles: s[t][j] = S[q = q0+kg*4+j][k = kt*32 + t*16 + lr]
    f32x4 s[2];
#pragma unroll
    for (int t = 0; t < 2; ++t) {
      const unsigned short* krow = base + (size_t)(bz * N_ + kt * 32 + t * 16 + lr) * QKVW_ + E_ + hh * HD_;
      short8 kf0 = *(const short8*)(krow + kg * 8);
      short8 kf1 = *(const short8*)(krow + 32 + kg * 8);
      f32x4 acc = (f32x4){0.f, 0.f, 0.f, 0.f};
      acc = __builtin_amdgcn_mfma_f32_16x16x32_bf16(qf[0], kf0, acc, 0, 0, 0);
      acc = __builtin_amdgcn_mfma_f32_16x16x32_bf16(qf[1], kf1, acc, 0, 0, 0);
      s[t] = acc;
    }
    float pm[2][4];
#pragma unroll
    for (int t = 0; t < 2; ++t) {
      int kglob = kt * 32 + t * 16 + lr;
#pragma unroll
      for (int j = 0; j < 4; ++j) {
        int qglob = q0 + kg * 4 + j;
        pm[t][j] = (kglob <= qglob) ? s[t][j] * 0.125f : -INFINITY;
      }
    }
    // online softmax (per q-row: reduce across the 16 lanes of the lr group)
#pragma unroll
    for (int j = 0; j < 4; ++j) {
      float tm = fmaxf(pm[0][j], pm[1][j]);
      tm = fmaxf(tm, __shfl_xor(tm, 1));
      tm = fmaxf(tm, __shfl_xor(tm, 2));
      tm = fmaxf(tm, __shfl_xor(tm, 4));
      tm = fmaxf(tm, __shfl_xor(tm, 8));
      float mnew = fmaxf(mrow[j], tm);      // finite after first tile (diag always unmasked)
      float alpha = __expf(mrow[j] - mnew);
      float p0 = __expf(pm[0][j] - mnew);
      float p1 = __expf(pm[1][j] - mnew);
      float rs = p0 + p1;
      rs += __shfl_xor(rs, 1);
      rs += __shfl_xor(rs, 2);
      rs += __shfl_xor(rs, 4);
      rs += __shfl_xor(rs, 8);
      lsum[j] = lsum[j] * alpha + rs;
      mrow[j] = mnew;
#pragma unroll
      for (int db = 0; db < 4; ++db) accO[db][j] *= alpha;
      P[(kg * 4 + j) * PRS_ + lr]      = f2bf(p0);
      P[(kg * 4 + j) * PRS_ + 16 + lr] = f2bf(p1);
    }
    __syncthreads();
    // P A-frag: element j = P[q=lr][k=kg*8+j]
    short8 pa = *(const short8*)&P[lr * PRS_ + kg * 8];
    // PV: accO[db][j] += sum_k P[q][k] * Vt[db*16+lr][kt*32+k]
#pragma unroll
    for (int db = 0; db < 4; ++db) {
      short8 vf = *(const short8*)(vtb + (size_t)(db * 16 + lr) * N_ + kt * 32 + kg * 8);
      accO[db] = __builtin_amdgcn_mfma_f32_16x16x32_bf16(pa, vf, accO[db], 0, 0, 0);
    }
    __syncthreads();
  }
  unsigned short* ob = (unsigned short*)o;
#pragma unroll
  for (int j = 0; j < 4; ++j) {
    float inv = 1.f / lsum[j];
    size_t orow = (size_t)(bz * N_ + q0 + kg * 4 + j) * E_ + hh * HD_;
#pragma unroll
    for (int db = 0; db < 4; ++db)
      ob[orow + db * 16 + lr] = f2bf(accO[db][j] * inv);
  }
}

extern "C" void kernel_launch(void* const* d_in, const int* in_sizes, int n_in,
                              void* d_out, int out_size, void* d_ws, size_t ws_size,
                              hipStream_t stream) {
  const int*   x     = (const int*)  d_in[0];
  const float* tok   = (const float*)d_in[1];
  const float* wq    = (const float*)d_in[2];
  const float* wk    = (const float*)d_in[3];
  const float* wv    = (const float*)d_in[4];
  const float* wo    = (const float*)d_in[5];
  const float* bo    = (const float*)d_in[6];
  const float* ln1g  = (const float*)d_in[7];
  const float* ln1b  = (const float*)d_in[8];
  const float* ln2g  = (const float*)d_in[9];
  const float* ln2b  = (const float*)d_in[10];
  const float* w1    = (const float*)d_in[11];
  const float* b1    = (const float*)d_in[12];
  const float* w2    = (const float*)d_in[13];
  const float* b2    = (const float*)d_in[14];
  const float* lnfg  = (const float*)d_in[15];
  const float* lnfb  = (const float*)d_in[16];
  const float* whead = (const float*)d_in[17];
  float* out = (float*)d_out;

  char* wsb = (char*)d_ws;
  size_t off = 0;
  auto alloc = [&](size_t bytes) -> void* {
    void* p = wsb + off; off += (bytes + 255) & ~(size_t)255; return p;
  };
  float*           h        = (float*)          alloc((size_t)M_ * E_ * 4);
  __hip_bfloat16*  y_bf     = (__hip_bfloat16*) alloc((size_t)M_ * E_ * 2);
  __hip_bfloat16*  qkv_bf   = (__hip_bfloat16*) alloc((size_t)M_ * QKVW_ * 2);
  __hip_bfloat16*  vt_bf    = (__hip_bfloat16*) alloc((size_t)B_ * H_ * HD_ * N_ * 2);
  __hip_bfloat16*  o_bf     = (__hip_bfloat16*) alloc((size_t)M_ * E_ * 2);
  __hip_bfloat16*  mid_bf   = (__hip_bfloat16*) alloc((size_t)M_ * FF_ * 2);
  __hip_bfloat16*  whead_bt = (__hip_bfloat16*) alloc((size_t)VPAD_ * E_ * 2);
  __hip_bfloat16*  qkvw_bt  = (__hip_bfloat16*) alloc((size_t)QKVW_ * E_ * 2);
  __hip_bfloat16*  wo_bt    = (__hip_bfloat16*) alloc((size_t)E_ * E_ * 2);
  __hip_bfloat16*  w1_bt    = (__hip_bfloat16*) alloc((size_t)FF_ * E_ * 2);
  __hip_bfloat16*  w2_bt    = (__hip_bfloat16*) alloc((size_t)E_ * FF_ * 2);

  dim3 blk(256);

  embed_kernel<<<(B_ * N_ * E_ + 255) / 256, blk, 0, stream>>>(x, tok, h);
  transpose_cast_kernel<<<dim3(E_ / 64, VPAD_ / 64), blk, 0, stream>>>(whead, whead_bt, E_, V_);

  dim3 gqkv(QKVW_ / 128, M_ / 128);
  dim3 gproj(E_ / 128, M_ / 128);
  dim3 gffn1(FF_ / 128, M_ / 128);
  dim3 gvt(N_ / 64, H_, B_);
  dim3 gfa(N_ / 16, H_, B_);

  for (int l = 0; l < L_; ++l) {
    const size_t we = (size_t)l * E_ * E_;
    transpose_cast_kernel<<<dim3(12, 12), blk, 0, stream>>>(wq + we, qkvw_bt, E_, E_);
    transpose_cast_kernel<<<dim3(12, 12), blk, 0, stream>>>(wk + we, qkvw_bt + (size_t)E_ * E_, E_, E_);
    transpose_cast_kernel<<<dim3(12, 12), blk, 0, stream>>>(wv + we, qkvw_bt + (size_t)2 * E_ * E_, E_, E_);
    transpose_cast_kernel<<<dim3(12, 12), blk, 0, stream>>>(wo + we, wo_bt, E_, E_);
    transpose_cast_kernel<<<dim3(12, 48), blk, 0, stream>>>(w1 + (size_t)l * E_ * FF_, w1_bt, E_, FF_);
    transpose_cast_kernel<<<dim3(48, 12), blk, 0, stream>>>(w2 + (size_t)l * FF_ * E_, w2_bt, FF_, E_);

    layernorm_kernel<<<M_, blk, 0, stream>>>(h, y_bf, ln1g + (size_t)l * E_, ln1b + (size_t)l * E_);
    gemm_bt_kernel<<<gqkv, blk, 0, stream>>>(y_bf, qkvw_bt, nullptr, nullptr, nullptr, qkv_bf,
                                             QKVW_, E_, 0);
    vtrans_kernel<<<gvt, blk, 0, stream>>>(qkv_bf, vt_bf);
    fattn_kernel<<<gfa, dim3(64), 0, stream>>>(qkv_bf, vt_bf, o_bf);
    gemm_bt_kernel<<<gproj, blk, 0, stream>>>(o_bf, wo_bt, bo + (size_t)l * E_, h, h, nullptr,
                                              E_, E_, 0);
    layernorm_kernel<<<M_, blk, 0, stream>>>(h, y_bf, ln2g + (size_t)l * E_, ln2b + (size_t)l * E_);
    gemm_bt_kernel<<<gffn1, blk, 0, stream>>>(y_bf, w1_bt, b1 + (size_t)l * FF_, nullptr, nullptr, mid_bf,
                                              FF_, E_, 1);
    gemm_bt_kernel<<<gproj, blk, 0, stream>>>(mid_bf, w2_bt, b2 + (size_t)l * E_, h, h, nullptr,
                                              E_, FF_, 0);
  }

  layernorm_kernel<<<M_, blk, 0, stream>>>(h, y_bf, lnfg, lnfb);
  gemm_bt_kernel<<<dim3(VPAD_ / 128, M_ / 128), blk, 0, stream>>>(y_bf, whead_bt, nullptr, nullptr, out, nullptr,
                                                                  V_, E_, 0);
}

// Round 4
// 2064.369 us; speedup vs baseline: 6.6298x; 1.0942x over previous
//
#include <hip/hip_runtime.h>
#include <hip/hip_bf16.h>
#include <math.h>

#define B_  2
#define N_  1024
#define E_  768
#define H_  12
#define HD_ 64
#define L_  6
#define FF_ 3072
#define V_  50257
#define VPAD_ 50304
#define QKVW_ 2304
#define M_  (B_ * N_)   // 2048

typedef short short8 __attribute__((ext_vector_type(8)));
typedef float f32x4 __attribute__((ext_vector_type(4)));

__device__ __forceinline__ float gelu_f(float x) {
  return 0.5f * x * (1.0f + tanhf(0.7978845608028654f * (x + 0.044715f * x * x * x)));
}

__device__ __forceinline__ float bf2f(unsigned short u) {
  return __uint_as_float((unsigned)u << 16);
}

__device__ __forceinline__ unsigned short f2bf(float f) {
  __hip_bfloat16 b = __float2bfloat16(f);
  return *reinterpret_cast<unsigned short*>(&b);
}

__device__ __forceinline__ void async_ld16(const void* g, void* l) {
  __builtin_amdgcn_global_load_lds(
      (const __attribute__((address_space(1))) void*)g,
      (__attribute__((address_space(3))) void*)l, 16, 0, 0);
}

// ---------------- embed ----------------
__global__ __launch_bounds__(256) void embed_kernel(const int* __restrict__ x,
    const float* __restrict__ tok, float* __restrict__ h) {
  int idx = blockIdx.x * 256 + threadIdx.x;
  const int total = B_ * N_ * E_;
  if (idx >= total) return;
  int e  = idx % E_;
  int bn = idx / E_;
  int n  = bn % N_;
  int t  = x[bn];
  float freq = expf(-9.210340371976184f * (float)(2 * e) / (float)E_);
  float arg  = (float)n * freq;
  float pe   = (e & 1) ? cosf(arg) : sinf(arg);
  h[idx] = tok[(size_t)t * E_ + e] + pe;
}

// ---------------- layernorm: fp32 in -> bf16 out ----------------
__global__ __launch_bounds__(256) void layernorm_kernel(const float* __restrict__ in,
    __hip_bfloat16* __restrict__ out, const float* __restrict__ g, const float* __restrict__ b) {
  int row = blockIdx.x;
  const float* xr = in + (size_t)row * E_;
  __shared__ float red[256];
  int tid = threadIdx.x;
  float s = 0.f, ss = 0.f;
  for (int e = tid; e < E_; e += 256) { float v = xr[e]; s += v; ss += v * v; }
  red[tid] = s; __syncthreads();
  for (int o = 128; o > 0; o >>= 1) { if (tid < o) red[tid] += red[tid + o]; __syncthreads(); }
  float mean = red[0] / (float)E_;
  __syncthreads();
  red[tid] = ss; __syncthreads();
  for (int o = 128; o > 0; o >>= 1) { if (tid < o) red[tid] += red[tid + o]; __syncthreads(); }
  float var = red[0] / (float)E_ - mean * mean;
  float inv = rsqrtf(var + 1e-5f);
  for (int e = tid; e < E_; e += 256)
    out[(size_t)row * E_ + e] = __float2bfloat16(g[e] * (xr[e] - mean) * inv + b[e]);
}

// ---------------- transpose + cast (head weight): in[K][Nn] fp32 -> out[Npad][K] bf16 ----------------
__global__ __launch_bounds__(256) void transpose_cast_kernel(const float* __restrict__ in,
    __hip_bfloat16* __restrict__ out, int K, int Nn) {
  __shared__ float t[64][65];
  int k0 = blockIdx.x * 64, n0 = blockIdx.y * 64;
  int tid = threadIdx.x;
  int c = tid & 63, rg = tid >> 6;
#pragma unroll
  for (int i = 0; i < 16; ++i) {
    int r = rg * 16 + i;
    int n = n0 + c;
    t[r][c] = (n < Nn) ? in[(size_t)(k0 + r) * Nn + n] : 0.0f;
  }
  __syncthreads();
#pragma unroll
  for (int i = 0; i < 16; ++i) {
    int ro = rg * 16 + i;
    out[(size_t)(n0 + ro) * K + (k0 + c)] = __float2bfloat16(t[c][ro]);
  }
}

// ---------------- fused per-layer weight transposes (wq,wk,wv,wo,w1,w2) ----------------
// tiles: wq/wk/wv/wo 144 each (12x12), w1 576 (12 kt x 48 nt), w2 576 (48 kt x 12 nt)
__global__ __launch_bounds__(256) void wtrans_kernel(
    const float* __restrict__ wq, const float* __restrict__ wk,
    const float* __restrict__ wv, const float* __restrict__ wo,
    const float* __restrict__ w1, const float* __restrict__ w2,
    __hip_bfloat16* __restrict__ qkvw_bt, __hip_bfloat16* __restrict__ wo_bt,
    __hip_bfloat16* __restrict__ w1_bt, __hip_bfloat16* __restrict__ w2_bt) {
  int t = blockIdx.x;
  const float* src; __hip_bfloat16* dst; int K;
  if (t < 576) {
    K = E_;
    int which = t / 144; t -= which * 144;
    if (which == 0)      { src = wq; dst = qkvw_bt; }
    else if (which == 1) { src = wk; dst = qkvw_bt + (size_t)E_ * E_; }
    else if (which == 2) { src = wv; dst = qkvw_bt + (size_t)2 * E_ * E_; }
    else                 { src = wo; dst = wo_bt; }
  } else if (t < 1152) {
    t -= 576; K = E_; src = w1; dst = w1_bt;          // Nn = FF_
  } else {
    t -= 1152; K = FF_; src = w2; dst = w2_bt;        // Nn = E_
  }
  int ntk = K / 64;
  int kt = t % ntk, nt = t / ntk;
  int Nn = (K == FF_) ? E_ : ((dst == w1_bt) ? FF_ : ((dst == qkvw_bt || dst == wo_bt ||
            dst == qkvw_bt + (size_t)E_ * E_ || dst == qkvw_bt + (size_t)2 * E_ * E_) ? E_ : E_));
  // Nn: wq/wk/wv/wo -> 768, w1 -> 3072, w2 -> 768
  if (src == w1) Nn = FF_;
  else Nn = E_;
  int k0 = kt * 64, n0 = nt * 64;
  __shared__ float tt[64][65];
  int tid = threadIdx.x;
  int c = tid & 63, rg = tid >> 6;
#pragma unroll
  for (int i = 0; i < 16; ++i) {
    int r = rg * 16 + i;
    tt[r][c] = src[(size_t)(k0 + r) * Nn + (n0 + c)];
  }
  __syncthreads();
#pragma unroll
  for (int i = 0; i < 16; ++i) {
    int ro = rg * 16 + i;
    dst[(size_t)(n0 + ro) * K + (k0 + c)] = __float2bfloat16(tt[c][ro]);
  }
}

// ---------------- MFMA GEMM: C[M,Nn] = A[M,K] @ Bt[Npad,K]^T ----------------
// 128x128 tile, BK=32, 4 waves, both-sides LDS XOR swizzle (rule 21),
// optional: panel-major+XCD block remap (nrt>0), nontemporal Cf store (flags&2),
// GELU (flags&1), V-columns redirected to vt[B][H][HD][N] (vt != nullptr).
__global__ __launch_bounds__(256) void gemm_bt_kernel(
    const __hip_bfloat16* __restrict__ A, const __hip_bfloat16* __restrict__ Bt,
    const float* __restrict__ bias, const float* __restrict__ R,
    float* __restrict__ Cf, __hip_bfloat16* __restrict__ Cb,
    __hip_bfloat16* __restrict__ vt,
    int Nn, int K, int flags, int nrt) {
  __shared__ __align__(16) unsigned short As[128 * 32];
  __shared__ __align__(16) unsigned short Bs[128 * 32];
  int tid = threadIdx.x;
  int w = tid >> 6, l = tid & 63;
  int wr = w >> 1, wc = w & 1;
  int bx, by;
  if (nrt > 0) {                 // 1-D launch: XCD-chunked, column-panel-major
    int bid = blockIdx.x;
    int q = gridDim.x >> 3;      // gridDim.x % 8 == 0
    int nb = (bid & 7) * q + (bid >> 3);
    bx = nb / nrt;
    by = nb - bx * nrt;
  } else { bx = blockIdx.x; by = blockIdx.y; }
  int row0 = by * 128, col0 = bx * 128;
  int lr = l & 15, kg = l >> 4;
  const unsigned short* Ag = (const unsigned short*)A;
  const unsigned short* Bg = (const unsigned short*)Bt;
  int srow = l >> 2;                         // LDS row within 16-row stripe
  int schunk = (l & 3) ^ (srow & 3);         // pre-swizzled source 16B-chunk
  int scol = schunk * 8;
  int rchunk = (kg ^ (lr & 3)) * 8;          // swizzled read chunk (shorts)

  f32x4 acc[4][4];
#pragma unroll
  for (int m = 0; m < 4; ++m)
#pragma unroll
    for (int n = 0; n < 4; ++n) acc[m][n] = (f32x4){0.f, 0.f, 0.f, 0.f};

  for (int k0 = 0; k0 < K; k0 += 32) {
#pragma unroll
    for (int i = 0; i < 2; ++i) {
      int rbase = i * 64 + w * 16;
      async_ld16(Ag + (size_t)(row0 + rbase + srow) * K + k0 + scol, &As[rbase * 32]);
      async_ld16(Bg + (size_t)(col0 + rbase + srow) * K + k0 + scol, &Bs[rbase * 32]);
    }
    __syncthreads();
    short8 af[4], bf[4];
#pragma unroll
    for (int m = 0; m < 4; ++m)
      af[m] = *(const short8*)&As[(wr * 64 + m * 16 + lr) * 32 + rchunk];
#pragma unroll
    for (int n = 0; n < 4; ++n)
      bf[n] = *(const short8*)&Bs[(wc * 64 + n * 16 + lr) * 32 + rchunk];
#pragma unroll
    for (int m = 0; m < 4; ++m)
#pragma unroll
      for (int n = 0; n < 4; ++n)
        acc[m][n] = __builtin_amdgcn_mfma_f32_16x16x32_bf16(af[m], bf[n], acc[m][n], 0, 0, 0);
    __syncthreads();
  }

  unsigned short* vtb = (unsigned short*)vt;
#pragma unroll
  for (int n = 0; n < 4; ++n) {
    int col = col0 + wc * 64 + n * 16 + lr;
    if (col >= Nn) continue;
    float bv = bias ? bias[col] : 0.f;
    bool to_vt = (vtb != nullptr) && (col >= 2 * E_);
    int hh = 0, dd = 0;
    if (to_vt) { int c2 = col - 2 * E_; hh = c2 >> 6; dd = c2 & 63; }
#pragma unroll
    for (int m = 0; m < 4; ++m) {
#pragma unroll
      for (int j = 0; j < 4; ++j) {
        int row = row0 + wr * 64 + m * 16 + kg * 4 + j;
        float val = acc[m][n][j] + bv;
        if (flags & 1) val = gelu_f(val);
        if (R) val += R[(size_t)row * Nn + col];
        if (Cf) {
          if (flags & 2) __builtin_nontemporal_store(val, &Cf[(size_t)row * Nn + col]);
          else Cf[(size_t)row * Nn + col] = val;
        }
        if (to_vt) {
          int bz = row >> 10, nn = row & (N_ - 1);
          vtb[((size_t)(bz * H_ + hh) * HD_ + dd) * N_ + nn] = f2bf(val);
        } else if (Cb) {
          Cb[(size_t)row * Nn + col] = __float2bfloat16(val);
        }
      }
    }
  }
}

// ---------------- flash attention: 1 wave/block, 16 q-rows, 32-key steps ----------------
#define PRS_ 40
__global__ __launch_bounds__(64) void fattn_kernel(
    const __hip_bfloat16* __restrict__ qkv, const __hip_bfloat16* __restrict__ vt,
    __hip_bfloat16* __restrict__ o) {
  int qt = blockIdx.x, hh = blockIdx.y, bz = blockIdx.z;
  int q0 = qt * 16;
  int l = threadIdx.x;
  int lr = l & 15, kg = l >> 4;
  const unsigned short* base = (const unsigned short*)qkv;
  const unsigned short* vtb = (const unsigned short*)vt + ((size_t)(bz * H_ + hh)) * HD_ * N_;
  __shared__ __align__(16) unsigned short P[16 * PRS_];

  short8 qf[2];
  const unsigned short* qrow = base + (size_t)(bz * N_ + q0 + lr) * QKVW_ + hh * HD_;
#pragma unroll
  for (int c = 0; c < 2; ++c) qf[c] = *(const short8*)(qrow + c * 32 + kg * 8);

  float mrow[4], lsum[4];
  f32x4 accO[4];
#pragma unroll
  for (int j = 0; j < 4; ++j) { mrow[j] = -INFINITY; lsum[j] = 0.f; }
#pragma unroll
  for (int db = 0; db < 4; ++db) accO[db] = (f32x4){0.f, 0.f, 0.f, 0.f};

  int nsteps = (q0 + 16 + 31) / 32;
  for (int kt = 0; kt < nsteps; ++kt) {
    f32x4 s[2];
#pragma unroll
    for (int t = 0; t < 2; ++t) {
      const unsigned short* krow = base + (size_t)(bz * N_ + kt * 32 + t * 16 + lr) * QKVW_ + E_ + hh * HD_;
      short8 kf0 = *(const short8*)(krow + kg * 8);
      short8 kf1 = *(const short8*)(krow + 32 + kg * 8);
      f32x4 acc = (f32x4){0.f, 0.f, 0.f, 0.f};
      acc = __builtin_amdgcn_mfma_f32_16x16x32_bf16(qf[0], kf0, acc, 0, 0, 0);
      acc = __builtin_amdgcn_mfma_f32_16x16x32_bf16(qf[1], kf1, acc, 0, 0, 0);
      s[t] = acc;
    }
    float pm[2][4];
#pragma unroll
    for (int t = 0; t < 2; ++t) {
      int kglob = kt * 32 + t * 16 + lr;
#pragma unroll
      for (int j = 0; j < 4; ++j) {
        int qglob = q0 + kg * 4 + j;
        pm[t][j] = (kglob <= qglob) ? s[t][j] * 0.125f : -INFINITY;
      }
    }
#pragma unroll
    for (int j = 0; j < 4; ++j) {
      float tm = fmaxf(pm[0][j], pm[1][j]);
      tm = fmaxf(tm, __shfl_xor(tm, 1));
      tm = fmaxf(tm, __shfl_xor(tm, 2));
      tm = fmaxf(tm, __shfl_xor(tm, 4));
      tm = fmaxf(tm, __shfl_xor(tm, 8));
      float mnew = fmaxf(mrow[j], tm);
      float alpha = __expf(mrow[j] - mnew);
      float p0 = __expf(pm[0][j] - mnew);
      float p1 = __expf(pm[1][j] - mnew);
      float rs = p0 + p1;
      rs += __shfl_xor(rs, 1);
      rs += __shfl_xor(rs, 2);
      rs += __shfl_xor(rs, 4);
      rs += __shfl_xor(rs, 8);
      lsum[j] = lsum[j] * alpha + rs;
      mrow[j] = mnew;
#pragma unroll
      for (int db = 0; db < 4; ++db) accO[db][j] *= alpha;
      P[(kg * 4 + j) * PRS_ + lr]      = f2bf(p0);
      P[(kg * 4 + j) * PRS_ + 16 + lr] = f2bf(p1);
    }
    __syncthreads();
    short8 pa = *(const short8*)&P[lr * PRS_ + kg * 8];
#pragma unroll
    for (int db = 0; db < 4; ++db) {
      short8 vf = *(const short8*)(vtb + (size_t)(db * 16 + lr) * N_ + kt * 32 + kg * 8);
      accO[db] = __builtin_amdgcn_mfma_f32_16x16x32_bf16(pa, vf, accO[db], 0, 0, 0);
    }
    __syncthreads();
  }
  unsigned short* ob = (unsigned short*)o;
#pragma unroll
  for (int j = 0; j < 4; ++j) {
    float inv = 1.f / lsum[j];
    size_t orow = (size_t)(bz * N_ + q0 + kg * 4 + j) * E_ + hh * HD_;
#pragma unroll
    for (int db = 0; db < 4; ++db)
      ob[orow + db * 16 + lr] = f2bf(accO[db][j] * inv);
  }
}

extern "C" void kernel_launch(void* const* d_in, const int* in_sizes, int n_in,
                              void* d_out, int out_size, void* d_ws, size_t ws_size,
                              hipStream_t stream) {
  const int*   x     = (const int*)  d_in[0];
  const float* tok   = (const float*)d_in[1];
  const float* wq    = (const float*)d_in[2];
  const float* wk    = (const float*)d_in[3];
  const float* wv    = (const float*)d_in[4];
  const float* wo    = (const float*)d_in[5];
  const float* bo    = (const float*)d_in[6];
  const float* ln1g  = (const float*)d_in[7];
  const float* ln1b  = (const float*)d_in[8];
  const float* ln2g  = (const float*)d_in[9];
  const float* ln2b  = (const float*)d_in[10];
  const float* w1    = (const float*)d_in[11];
  const float* b1    = (const float*)d_in[12];
  const float* w2    = (const float*)d_in[13];
  const float* b2    = (const float*)d_in[14];
  const float* lnfg  = (const float*)d_in[15];
  const float* lnfb  = (const float*)d_in[16];
  const float* whead = (const float*)d_in[17];
  float* out = (float*)d_out;

  char* wsb = (char*)d_ws;
  size_t off = 0;
  auto alloc = [&](size_t bytes) -> void* {
    void* p = wsb + off; off += (bytes + 255) & ~(size_t)255; return p;
  };
  float*           h        = (float*)          alloc((size_t)M_ * E_ * 4);
  __hip_bfloat16*  y_bf     = (__hip_bfloat16*) alloc((size_t)M_ * E_ * 2);
  __hip_bfloat16*  qkv_bf   = (__hip_bfloat16*) alloc((size_t)M_ * QKVW_ * 2);
  __hip_bfloat16*  vt_bf    = (__hip_bfloat16*) alloc((size_t)B_ * H_ * HD_ * N_ * 2);
  __hip_bfloat16*  o_bf     = (__hip_bfloat16*) alloc((size_t)M_ * E_ * 2);
  __hip_bfloat16*  mid_bf   = (__hip_bfloat16*) alloc((size_t)M_ * FF_ * 2);
  __hip_bfloat16*  whead_bt = (__hip_bfloat16*) alloc((size_t)VPAD_ * E_ * 2);
  __hip_bfloat16*  qkvw_bt  = (__hip_bfloat16*) alloc((size_t)QKVW_ * E_ * 2);
  __hip_bfloat16*  wo_bt    = (__hip_bfloat16*) alloc((size_t)E_ * E_ * 2);
  __hip_bfloat16*  w1_bt    = (__hip_bfloat16*) alloc((size_t)FF_ * E_ * 2);
  __hip_bfloat16*  w2_bt    = (__hip_bfloat16*) alloc((size_t)E_ * FF_ * 2);

  dim3 blk(256);

  embed_kernel<<<(B_ * N_ * E_ + 255) / 256, blk, 0, stream>>>(x, tok, h);
  transpose_cast_kernel<<<dim3(E_ / 64, VPAD_ / 64), blk, 0, stream>>>(whead, whead_bt, E_, V_);

  dim3 gqkv(QKVW_ / 128, M_ / 128);
  dim3 gproj(E_ / 128, M_ / 128);
  dim3 gffn1(FF_ / 128, M_ / 128);
  dim3 gfa(N_ / 16, H_, B_);

  for (int l = 0; l < L_; ++l) {
    const size_t we = (size_t)l * E_ * E_;
    wtrans_kernel<<<1728, blk, 0, stream>>>(wq + we, wk + we, wv + we, wo + we,
        w1 + (size_t)l * E_ * FF_, w2 + (size_t)l * FF_ * E_,
        qkvw_bt, wo_bt, w1_bt, w2_bt);

    layernorm_kernel<<<M_, blk, 0, stream>>>(h, y_bf, ln1g + (size_t)l * E_, ln1b + (size_t)l * E_);
    gemm_bt_kernel<<<gqkv, blk, 0, stream>>>(y_bf, qkvw_bt, nullptr, nullptr, nullptr, qkv_bf,
                                             vt_bf, QKVW_, E_, 0, 0);
    fattn_kernel<<<gfa, dim3(64), 0, stream>>>(qkv_bf, vt_bf, o_bf);
    gemm_bt_kernel<<<gproj, blk, 0, stream>>>(o_bf, wo_bt, bo + (size_t)l * E_, h, h, nullptr,
                                              nullptr, E_, E_, 0, 0);
    layernorm_kernel<<<M_, blk, 0, stream>>>(h, y_bf, ln2g + (size_t)l * E_, ln2b + (size_t)l * E_);
    gemm_bt_kernel<<<gffn1, blk, 0, stream>>>(y_bf, w1_bt, b1 + (size_t)l * FF_, nullptr, nullptr, mid_bf,
                                              nullptr, FF_, E_, 1, 0);
    gemm_bt_kernel<<<gproj, blk, 0, stream>>>(mid_bf, w2_bt, b2 + (size_t)l * E_, h, h, nullptr,
                                              nullptr, E_, FF_, 0, 0);
  }

  layernorm_kernel<<<M_, blk, 0, stream>>>(h, y_bf, lnfg, lnfb);
  // head: 1-D grid, panel-major + XCD-chunked remap, nontemporal C stores
  gemm_bt_kernel<<<dim3((VPAD_ / 128) * (M_ / 128)), blk, 0, stream>>>(
      y_bf, whead_bt, nullptr, nullptr, out, nullptr, nullptr, V_, E_, 2, M_ / 128);
}

// Round 5
// 1688.840 us; speedup vs baseline: 8.1040x; 1.2224x over previous
//
#include <hip/hip_runtime.h>
#include <hip/hip_bf16.h>
#include <math.h>

#define B_  2
#define N_  1024
#define E_  768
#define H_  12
#define HD_ 64
#define L_  6
#define FF_ 3072
#define V_  50257
#define VPAD_ 50304
#define QKVW_ 2304
#define M_  (B_ * N_)   // 2048

// per-layer transposed-weight slab (bf16 element offsets)
#define OFF_QKV_ 0
#define OFF_WO_  (QKVW_ * E_)
#define OFF_W1_  (OFF_WO_ + E_ * E_)
#define OFF_W2_  (OFF_W1_ + FF_ * E_)
#define WSLAB_   ((size_t)(OFF_W2_ + E_ * FF_))   // 7077888 elems

typedef short short8 __attribute__((ext_vector_type(8)));
typedef float f32x4 __attribute__((ext_vector_type(4)));

__device__ __forceinline__ float gelu_f(float x) {
  return 0.5f * x * (1.0f + tanhf(0.7978845608028654f * (x + 0.044715f * x * x * x)));
}

__device__ __forceinline__ unsigned short f2bf(float f) {
  __hip_bfloat16 b = __float2bfloat16(f);
  return *reinterpret_cast<unsigned short*>(&b);
}

__device__ __forceinline__ void async_ld16(const void* g, void* l) {
  __builtin_amdgcn_global_load_lds(
      (const __attribute__((address_space(1))) void*)g,
      (__attribute__((address_space(3))) void*)l, 16, 0, 0);
}

// ---------------- embed ----------------
__global__ __launch_bounds__(256) void embed_kernel(const int* __restrict__ x,
    const float* __restrict__ tok, float* __restrict__ h) {
  int idx = blockIdx.x * 256 + threadIdx.x;
  const int total = B_ * N_ * E_;
  if (idx >= total) return;
  int e  = idx % E_;
  int bn = idx / E_;
  int n  = bn % N_;
  int t  = x[bn];
  float freq = expf(-9.210340371976184f * (float)(2 * e) / (float)E_);
  float arg  = (float)n * freq;
  float pe   = (e & 1) ? cosf(arg) : sinf(arg);
  h[idx] = tok[(size_t)t * E_ + e] + pe;
}

// ---------------- layernorm: fp32 in -> bf16 out ----------------
__global__ __launch_bounds__(256) void layernorm_kernel(const float* __restrict__ in,
    __hip_bfloat16* __restrict__ out, const float* __restrict__ g, const float* __restrict__ b) {
  int row = blockIdx.x;
  const float* xr = in + (size_t)row * E_;
  __shared__ float red[256];
  int tid = threadIdx.x;
  float s = 0.f, ss = 0.f;
  for (int e = tid; e < E_; e += 256) { float v = xr[e]; s += v; ss += v * v; }
  red[tid] = s; __syncthreads();
  for (int o = 128; o > 0; o >>= 1) { if (tid < o) red[tid] += red[tid + o]; __syncthreads(); }
  float mean = red[0] / (float)E_;
  __syncthreads();
  red[tid] = ss; __syncthreads();
  for (int o = 128; o > 0; o >>= 1) { if (tid < o) red[tid] += red[tid + o]; __syncthreads(); }
  float var = red[0] / (float)E_ - mean * mean;
  float inv = rsqrtf(var + 1e-5f);
  for (int e = tid; e < E_; e += 256)
    out[(size_t)row * E_ + e] = __float2bfloat16(g[e] * (xr[e] - mean) * inv + b[e]);
}

// ---------------- transpose + cast (head weight) ----------------
__global__ __launch_bounds__(256) void transpose_cast_kernel(const float* __restrict__ in,
    __hip_bfloat16* __restrict__ out, int K, int Nn) {
  __shared__ float t[64][65];
  int k0 = blockIdx.x * 64, n0 = blockIdx.y * 64;
  int tid = threadIdx.x;
  int c = tid & 63, rg = tid >> 6;
#pragma unroll
  for (int i = 0; i < 16; ++i) {
    int r = rg * 16 + i;
    int n = n0 + c;
    t[r][c] = (n < Nn) ? in[(size_t)(k0 + r) * Nn + n] : 0.0f;
  }
  __syncthreads();
#pragma unroll
  for (int i = 0; i < 16; ++i) {
    int ro = rg * 16 + i;
    out[(size_t)(n0 + ro) * K + (k0 + c)] = __float2bfloat16(t[c][ro]);
  }
}

// ---------------- per-layer weight transposes, nl layers in one launch ----------------
// 1728 tiles/layer: qkv+wo 4*144, w1 576, w2 576
__global__ __launch_bounds__(256) void wtrans_kernel(
    const float* __restrict__ wq, const float* __restrict__ wk,
    const float* __restrict__ wv, const float* __restrict__ wo,
    const float* __restrict__ w1, const float* __restrict__ w2,
    __hip_bfloat16* __restrict__ out, int l0) {
  int bid = blockIdx.x;
  int lay = bid / 1728;
  int t = bid - lay * 1728;
  int lsrc = l0 + lay;
  __hip_bfloat16* ob = out + (size_t)lay * WSLAB_;
  const float* src; __hip_bfloat16* dst;
  int K, Nn, ntk;
  if (t < 576) {
    int which = t / 144; t -= which * 144;
    K = E_; Nn = E_; ntk = 12;
    if (which == 0)      { src = wq + (size_t)lsrc * E_ * E_; dst = ob + OFF_QKV_; }
    else if (which == 1) { src = wk + (size_t)lsrc * E_ * E_; dst = ob + OFF_QKV_ + (size_t)E_ * E_; }
    else if (which == 2) { src = wv + (size_t)lsrc * E_ * E_; dst = ob + OFF_QKV_ + (size_t)2 * E_ * E_; }
    else                 { src = wo + (size_t)lsrc * E_ * E_; dst = ob + OFF_WO_; }
  } else if (t < 1152) {
    t -= 576; K = E_; Nn = FF_; ntk = 12;
    src = w1 + (size_t)lsrc * E_ * FF_; dst = ob + OFF_W1_;
  } else {
    t -= 1152; K = FF_; Nn = E_; ntk = 48;
    src = w2 + (size_t)lsrc * FF_ * E_; dst = ob + OFF_W2_;
  }
  int kt = t % ntk, nt = t / ntk;
  int k0 = kt * 64, n0 = nt * 64;
  __shared__ float tt[64][65];
  int tid = threadIdx.x;
  int c = tid & 63, rg = tid >> 6;
#pragma unroll
  for (int i = 0; i < 16; ++i) {
    int r = rg * 16 + i;
    tt[r][c] = src[(size_t)(k0 + r) * Nn + n0 + c];
  }
  __syncthreads();
#pragma unroll
  for (int i = 0; i < 16; ++i) {
    int ro = rg * 16 + i;
    dst[(size_t)(n0 + ro) * K + (k0 + c)] = __float2bfloat16(tt[c][ro]);
  }
}

// ---------------- MFMA GEMM: C[128-rows x BN-cols per block] = A @ Bt^T ----------------
// BK=32, 4 waves. LDS XOR swizzle: src chunk (l&3)^((l>>4)&3), read chunk kg^((lr>>2)&3)
// -> 2 lanes per 4-bank group per quarter-wave (conflict-free per m136).
// flags&1: GELU. flags&2 (BN=128 only): head path - LDS-transposed coalesced nt stores.
// nrt>0: 1-D launch, XCD-chunked column-panel-major remap.
template<int BN>
__global__ __launch_bounds__(256) void gemm_bt_kernel(
    const __hip_bfloat16* __restrict__ A, const __hip_bfloat16* __restrict__ Bt,
    const float* __restrict__ bias, const float* __restrict__ R,
    float* __restrict__ Cf, __hip_bfloat16* __restrict__ Cb,
    __hip_bfloat16* __restrict__ vt,
    int Nn, int K, int flags, int nrt) {
  constexpr int NROWS = 128 + BN;
  __shared__ __align__(16) unsigned short SM[NROWS * 32];
  unsigned short* As = SM;
  unsigned short* Bs = SM + 128 * 32;
  int tid = threadIdx.x;
  int w = tid >> 6, l = tid & 63;
  constexpr int MF  = (BN == 128) ? 4 : 2;    // m-fragments per wave
  constexpr int WRT = (BN == 128) ? 64 : 32;  // wave row-tile
  int wr = (BN == 128) ? (w >> 1) : w;
  int wc = (BN == 128) ? (w & 1) : 0;
  int bx, by;
  if (nrt > 0) {
    int bid = blockIdx.x;
    int q = gridDim.x >> 3;
    int nb = (bid & 7) * q + (bid >> 3);
    bx = nb / nrt; by = nb - bx * nrt;
  } else { bx = blockIdx.x; by = blockIdx.y; }
  int row0 = by * 128, col0 = bx * BN;
  int lr = l & 15, kg = l >> 4;
  const unsigned short* Ag = (const unsigned short*)A;
  const unsigned short* Bg = (const unsigned short*)Bt;
  int srow = l >> 2;
  int scol = ((l & 3) ^ ((l >> 4) & 3)) * 8;     // pre-swizzled source chunk
  int rchunk = (kg ^ ((lr >> 2) & 3)) * 8;       // swizzled read chunk

  f32x4 acc[MF][4];
#pragma unroll
  for (int m = 0; m < MF; ++m)
#pragma unroll
    for (int n = 0; n < 4; ++n) acc[m][n] = (f32x4){0.f, 0.f, 0.f, 0.f};

  constexpr int NS = NROWS / 64;   // staging instructions per wave (4 or 3)
  for (int k0 = 0; k0 < K; k0 += 32) {
#pragma unroll
    for (int s = 0; s < NS; ++s) {
      int st = s * 4 + w;
      if (st < 8)
        async_ld16(Ag + (size_t)(row0 + st * 16 + srow) * K + k0 + scol, &As[st * 16 * 32]);
      else
        async_ld16(Bg + (size_t)(col0 + (st - 8) * 16 + srow) * K + k0 + scol, &Bs[(st - 8) * 16 * 32]);
    }
    __syncthreads();
    short8 af[MF], bf[4];
#pragma unroll
    for (int m = 0; m < MF; ++m)
      af[m] = *(const short8*)&As[(wr * WRT + m * 16 + lr) * 32 + rchunk];
#pragma unroll
    for (int n = 0; n < 4; ++n)
      bf[n] = *(const short8*)&Bs[(wc * 64 + n * 16 + lr) * 32 + rchunk];
#pragma unroll
    for (int m = 0; m < MF; ++m)
#pragma unroll
      for (int n = 0; n < 4; ++n)
        acc[m][n] = __builtin_amdgcn_mfma_f32_16x16x32_bf16(af[m], bf[n], acc[m][n], 0, 0, 0);
    __syncthreads();
  }

  if constexpr (BN == 128) {
    if (flags & 2) {
      // head epilogue: LDS-transpose 32 rows/pass, fully-coalesced nt stores
      float* Ls = (float*)SM;   // 32 x 128 fp32 = 16 KB
      bool nfull = (col0 + 128 <= Nn);
#pragma unroll
      for (int p = 0; p < 4; ++p) {
        __syncthreads();
        if (wr == (p >> 1)) {
          int mb = (p & 1) * 2;
#pragma unroll
          for (int m2 = 0; m2 < 2; ++m2)
#pragma unroll
            for (int n = 0; n < 4; ++n)
#pragma unroll
              for (int j = 0; j < 4; ++j)
                Ls[(m2 * 16 + kg * 4 + j) * 128 + wc * 64 + n * 16 + lr] = acc[mb + m2][n][j];
        }
        __syncthreads();
        int rbase = row0 + p * 32;
        if (nfull) {
#pragma unroll
          for (int i = 0; i < 16; ++i) {
            int idx = i * 256 + tid;
            int r = idx >> 7, c = idx & 127;
            __builtin_nontemporal_store(Ls[r * 128 + c], &Cf[(size_t)(rbase + r) * Nn + col0 + c]);
          }
        } else {
          for (int i = 0; i < 16; ++i) {
            int idx = i * 256 + tid;
            int r = idx >> 7, c = idx & 127;
            if (col0 + c < Nn)
              __builtin_nontemporal_store(Ls[r * 128 + c], &Cf[(size_t)(rbase + r) * Nn + col0 + c]);
          }
        }
      }
      return;
    }
  }

  unsigned short* vtb = (unsigned short*)vt;
#pragma unroll
  for (int n = 0; n < 4; ++n) {
    int col = col0 + wc * 64 + n * 16 + lr;
    if (col >= Nn) continue;
    float bv = bias ? bias[col] : 0.f;
    bool to_vt = (vtb != nullptr) && (col >= 2 * E_);
    int hh = 0, dd = 0;
    if (to_vt) { int c2 = col - 2 * E_; hh = c2 >> 6; dd = c2 & 63; }
#pragma unroll
    for (int m = 0; m < MF; ++m) {
#pragma unroll
      for (int j = 0; j < 4; ++j) {
        int row = row0 + wr * WRT + m * 16 + kg * 4 + j;
        float val = acc[m][n][j] + bv;
        if (flags & 1) val = gelu_f(val);
        if (R) val += R[(size_t)row * Nn + col];
        if (Cf) Cf[(size_t)row * Nn + col] = val;
        if (to_vt) {
          int bz = row >> 10, nn = row & (N_ - 1);
          vtb[((size_t)(bz * H_ + hh) * HD_ + dd) * N_ + nn] = f2bf(val);
        } else if (Cb) {
          Cb[(size_t)row * Nn + col] = __float2bfloat16(val);
        }
      }
    }
  }
}

// ---------------- flash attention: 1 wave/block, 16 q-rows, 32-key steps ----------------
#define PRS_ 40
__global__ __launch_bounds__(64) void fattn_kernel(
    const __hip_bfloat16* __restrict__ qkv, const __hip_bfloat16* __restrict__ vt,
    __hip_bfloat16* __restrict__ o) {
  int qt = blockIdx.x, hh = blockIdx.y, bz = blockIdx.z;
  int q0 = qt * 16;
  int l = threadIdx.x;
  int lr = l & 15, kg = l >> 4;
  const unsigned short* base = (const unsigned short*)qkv;
  const unsigned short* vtb = (const unsigned short*)vt + ((size_t)(bz * H_ + hh)) * HD_ * N_;
  __shared__ __align__(16) unsigned short P[16 * PRS_];

  short8 qf[2];
  const unsigned short* qrow = base + (size_t)(bz * N_ + q0 + lr) * QKVW_ + hh * HD_;
#pragma unroll
  for (int c = 0; c < 2; ++c) qf[c] = *(const short8*)(qrow + c * 32 + kg * 8);

  float mrow[4], lsum[4];
  f32x4 accO[4];
#pragma unroll
  for (int j = 0; j < 4; ++j) { mrow[j] = -INFINITY; lsum[j] = 0.f; }
#pragma unroll
  for (int db = 0; db < 4; ++db) accO[db] = (f32x4){0.f, 0.f, 0.f, 0.f};

  int nsteps = (q0 + 16 + 31) / 32;
  for (int kt = 0; kt < nsteps; ++kt) {
    f32x4 s[2];
#pragma unroll
    for (int t = 0; t < 2; ++t) {
      const unsigned short* krow = base + (size_t)(bz * N_ + kt * 32 + t * 16 + lr) * QKVW_ + E_ + hh * HD_;
      short8 kf0 = *(const short8*)(krow + kg * 8);
      short8 kf1 = *(const short8*)(krow + 32 + kg * 8);
      f32x4 acc = (f32x4){0.f, 0.f, 0.f, 0.f};
      acc = __builtin_amdgcn_mfma_f32_16x16x32_bf16(qf[0], kf0, acc, 0, 0, 0);
      acc = __builtin_amdgcn_mfma_f32_16x16x32_bf16(qf[1], kf1, acc, 0, 0, 0);
      s[t] = acc;
    }
    float pm[2][4];
#pragma unroll
    for (int t = 0; t < 2; ++t) {
      int kglob = kt * 32 + t * 16 + lr;
#pragma unroll
      for (int j = 0; j < 4; ++j) {
        int qglob = q0 + kg * 4 + j;
        pm[t][j] = (kglob <= qglob) ? s[t][j] * 0.125f : -INFINITY;
      }
    }
#pragma unroll
    for (int j = 0; j < 4; ++j) {
      float tm = fmaxf(pm[0][j], pm[1][j]);
      tm = fmaxf(tm, __shfl_xor(tm, 1));
      tm = fmaxf(tm, __shfl_xor(tm, 2));
      tm = fmaxf(tm, __shfl_xor(tm, 4));
      tm = fmaxf(tm, __shfl_xor(tm, 8));
      float mnew = fmaxf(mrow[j], tm);
      float alpha = __expf(mrow[j] - mnew);
      float p0 = __expf(pm[0][j] - mnew);
      float p1 = __expf(pm[1][j] - mnew);
      float rs = p0 + p1;
      rs += __shfl_xor(rs, 1);
      rs += __shfl_xor(rs, 2);
      rs += __shfl_xor(rs, 4);
      rs += __shfl_xor(rs, 8);
      lsum[j] = lsum[j] * alpha + rs;
      mrow[j] = mnew;
#pragma unroll
      for (int db = 0; db < 4; ++db) accO[db][j] *= alpha;
      P[(kg * 4 + j) * PRS_ + lr]      = f2bf(p0);
      P[(kg * 4 + j) * PRS_ + 16 + lr] = f2bf(p1);
    }
    __syncthreads();
    short8 pa = *(const short8*)&P[lr * PRS_ + kg * 8];
#pragma unroll
    for (int db = 0; db < 4; ++db) {
      short8 vf = *(const short8*)(vtb + (size_t)(db * 16 + lr) * N_ + kt * 32 + kg * 8);
      accO[db] = __builtin_amdgcn_mfma_f32_16x16x32_bf16(pa, vf, accO[db], 0, 0, 0);
    }
    __syncthreads();
  }
  unsigned short* ob = (unsigned short*)o;
#pragma unroll
  for (int j = 0; j < 4; ++j) {
    float inv = 1.f / lsum[j];
    size_t orow = (size_t)(bz * N_ + q0 + kg * 4 + j) * E_ + hh * HD_;
#pragma unroll
    for (int db = 0; db < 4; ++db)
      ob[orow + db * 16 + lr] = f2bf(accO[db][j] * inv);
  }
}

extern "C" void kernel_launch(void* const* d_in, const int* in_sizes, int n_in,
                              void* d_out, int out_size, void* d_ws, size_t ws_size,
                              hipStream_t stream) {
  const int*   x     = (const int*)  d_in[0];
  const float* tok   = (const float*)d_in[1];
  const float* wq    = (const float*)d_in[2];
  const float* wk    = (const float*)d_in[3];
  const float* wv    = (const float*)d_in[4];
  const float* wo    = (const float*)d_in[5];
  const float* bo    = (const float*)d_in[6];
  const float* ln1g  = (const float*)d_in[7];
  const float* ln1b  = (const float*)d_in[8];
  const float* ln2g  = (const float*)d_in[9];
  const float* ln2b  = (const float*)d_in[10];
  const float* w1    = (const float*)d_in[11];
  const float* b1    = (const float*)d_in[12];
  const float* w2    = (const float*)d_in[13];
  const float* b2    = (const float*)d_in[14];
  const float* lnfg  = (const float*)d_in[15];
  const float* lnfb  = (const float*)d_in[16];
  const float* whead = (const float*)d_in[17];
  float* out = (float*)d_out;

  char* wsb = (char*)d_ws;
  size_t off = 0;
  auto alloc = [&](size_t bytes) -> void* {
    void* p = wsb + off; off += (bytes + 255) & ~(size_t)255; return p;
  };
  float*           h        = (float*)          alloc((size_t)M_ * E_ * 4);
  __hip_bfloat16*  y_bf     = (__hip_bfloat16*) alloc((size_t)M_ * E_ * 2);
  __hip_bfloat16*  qkv_bf   = (__hip_bfloat16*) alloc((size_t)M_ * QKVW_ * 2);
  __hip_bfloat16*  vt_bf    = (__hip_bfloat16*) alloc((size_t)B_ * H_ * HD_ * N_ * 2);
  __hip_bfloat16*  o_bf     = (__hip_bfloat16*) alloc((size_t)M_ * E_ * 2);
  __hip_bfloat16*  mid_bf   = (__hip_bfloat16*) alloc((size_t)M_ * FF_ * 2);
  __hip_bfloat16*  whead_bt = (__hip_bfloat16*) alloc((size_t)VPAD_ * E_ * 2);
  // transposed-weight slab(s): all 6 layers if workspace allows, else 1 reused
  bool preall = (off + (size_t)6 * WSLAB_ * 2 <= ws_size);
  __hip_bfloat16* wslab = (__hip_bfloat16*) alloc(((size_t)(preall ? 6 : 1)) * WSLAB_ * 2);

  dim3 blk(256);

  embed_kernel<<<(B_ * N_ * E_ + 255) / 256, blk, 0, stream>>>(x, tok, h);
  transpose_cast_kernel<<<dim3(E_ / 64, VPAD_ / 64), blk, 0, stream>>>(whead, whead_bt, E_, V_);
  if (preall)
    wtrans_kernel<<<6 * 1728, blk, 0, stream>>>(wq, wk, wv, wo, w1, w2, wslab, 0);

  dim3 gqkv(QKVW_ / 128, M_ / 128);
  dim3 gffn1(FF_ / 128, M_ / 128);
  dim3 g64(E_ / 64, M_ / 128);
  dim3 gfa(N_ / 16, H_, B_);

  for (int l = 0; l < L_; ++l) {
    if (!preall)
      wtrans_kernel<<<1728, blk, 0, stream>>>(wq, wk, wv, wo, w1, w2, wslab, l);
    __hip_bfloat16* wb = wslab + (preall ? (size_t)l * WSLAB_ : 0);

    layernorm_kernel<<<M_, blk, 0, stream>>>(h, y_bf, ln1g + (size_t)l * E_, ln1b + (size_t)l * E_);
    gemm_bt_kernel<128><<<gqkv, blk, 0, stream>>>(y_bf, wb + OFF_QKV_, nullptr, nullptr,
        nullptr, qkv_bf, vt_bf, QKVW_, E_, 0, 0);
    fattn_kernel<<<gfa, dim3(64), 0, stream>>>(qkv_bf, vt_bf, o_bf);
    gemm_bt_kernel<64><<<g64, blk, 0, stream>>>(o_bf, wb + OFF_WO_, bo + (size_t)l * E_, h,
        h, nullptr, nullptr, E_, E_, 0, 0);
    layernorm_kernel<<<M_, blk, 0, stream>>>(h, y_bf, ln2g + (size_t)l * E_, ln2b + (size_t)l * E_);
    gemm_bt_kernel<128><<<gffn1, blk, 0, stream>>>(y_bf, wb + OFF_W1_, b1 + (size_t)l * FF_,
        nullptr, nullptr, mid_bf, nullptr, FF_, E_, 1, 0);
    gemm_bt_kernel<64><<<g64, blk, 0, stream>>>(mid_bf, wb + OFF_W2_, b2 + (size_t)l * E_, h,
        h, nullptr, nullptr, E_, FF_, 0, 0);
  }

  layernorm_kernel<<<M_, blk, 0, stream>>>(h, y_bf, lnfg, lnfb);
  gemm_bt_kernel<128><<<dim3((VPAD_ / 128) * (M_ / 128)), blk, 0, stream>>>(
      y_bf, whead_bt, nullptr, nullptr, out, nullptr, nullptr, V_, E_, 2, M_ / 128);
}

// Round 6
// 1565.003 us; speedup vs baseline: 8.7452x; 1.0791x over previous
//
#include <hip/hip_runtime.h>
#include <hip/hip_bf16.h>
#include <math.h>

#define B_  2
#define N_  1024
#define E_  768
#define H_  12
#define HD_ 64
#define L_  6
#define FF_ 3072
#define V_  50257
#define VPAD_ 50304
#define QKVW_ 2304
#define M_  (B_ * N_)   // 2048

// per-layer transposed-weight slab (bf16 element offsets)
#define OFF_QKV_ 0
#define OFF_WO_  (QKVW_ * E_)
#define OFF_W1_  (OFF_WO_ + E_ * E_)
#define OFF_W2_  (OFF_W1_ + FF_ * E_)
#define WSLAB_   ((size_t)(OFF_W2_ + E_ * FF_))   // 7077888 elems

typedef short short8 __attribute__((ext_vector_type(8)));
typedef float f32x4 __attribute__((ext_vector_type(4)));

__device__ __forceinline__ float gelu_f(float x) {
  return 0.5f * x * (1.0f + tanhf(0.7978845608028654f * (x + 0.044715f * x * x * x)));
}

__device__ __forceinline__ unsigned short f2bf(float f) {
  __hip_bfloat16 b = __float2bfloat16(f);
  return *reinterpret_cast<unsigned short*>(&b);
}

__device__ __forceinline__ void async_ld16(const void* g, void* l) {
  __builtin_amdgcn_global_load_lds(
      (const __attribute__((address_space(1))) void*)g,
      (__attribute__((address_space(3))) void*)l, 16, 0, 0);
}

// ---------------- embed ----------------
__global__ __launch_bounds__(256) void embed_kernel(const int* __restrict__ x,
    const float* __restrict__ tok, float* __restrict__ h) {
  int idx = blockIdx.x * 256 + threadIdx.x;
  const int total = B_ * N_ * E_;
  if (idx >= total) return;
  int e  = idx % E_;
  int bn = idx / E_;
  int n  = bn % N_;
  int t  = x[bn];
  float freq = expf(-9.210340371976184f * (float)(2 * e) / (float)E_);
  float arg  = (float)n * freq;
  float pe   = (e & 1) ? cosf(arg) : sinf(arg);
  h[idx] = tok[(size_t)t * E_ + e] + pe;
}

// ---------------- layernorm: fp32 in -> bf16 out ----------------
__global__ __launch_bounds__(256) void layernorm_kernel(const float* __restrict__ in,
    __hip_bfloat16* __restrict__ out, const float* __restrict__ g, const float* __restrict__ b) {
  int row = blockIdx.x;
  const float* xr = in + (size_t)row * E_;
  __shared__ float red[256];
  int tid = threadIdx.x;
  float s = 0.f, ss = 0.f;
  for (int e = tid; e < E_; e += 256) { float v = xr[e]; s += v; ss += v * v; }
  red[tid] = s; __syncthreads();
  for (int o = 128; o > 0; o >>= 1) { if (tid < o) red[tid] += red[tid + o]; __syncthreads(); }
  float mean = red[0] / (float)E_;
  __syncthreads();
  red[tid] = ss; __syncthreads();
  for (int o = 128; o > 0; o >>= 1) { if (tid < o) red[tid] += red[tid + o]; __syncthreads(); }
  float var = red[0] / (float)E_ - mean * mean;
  float inv = rsqrtf(var + 1e-5f);
  for (int e = tid; e < E_; e += 256)
    out[(size_t)row * E_ + e] = __float2bfloat16(g[e] * (xr[e] - mean) * inv + b[e]);
}

// ---------------- transpose + cast (head weight) ----------------
__global__ __launch_bounds__(256) void transpose_cast_kernel(const float* __restrict__ in,
    __hip_bfloat16* __restrict__ out, int K, int Nn) {
  __shared__ float t[64][65];
  int k0 = blockIdx.x * 64, n0 = blockIdx.y * 64;
  int tid = threadIdx.x;
  int c = tid & 63, rg = tid >> 6;
#pragma unroll
  for (int i = 0; i < 16; ++i) {
    int r = rg * 16 + i;
    int n = n0 + c;
    t[r][c] = (n < Nn) ? in[(size_t)(k0 + r) * Nn + n] : 0.0f;
  }
  __syncthreads();
#pragma unroll
  for (int i = 0; i < 16; ++i) {
    int ro = rg * 16 + i;
    out[(size_t)(n0 + ro) * K + (k0 + c)] = __float2bfloat16(t[c][ro]);
  }
}

// ---------------- per-layer weight transposes, nl layers in one launch ----------------
__global__ __launch_bounds__(256) void wtrans_kernel(
    const float* __restrict__ wq, const float* __restrict__ wk,
    const float* __restrict__ wv, const float* __restrict__ wo,
    const float* __restrict__ w1, const float* __restrict__ w2,
    __hip_bfloat16* __restrict__ out, int l0) {
  int bid = blockIdx.x;
  int lay = bid / 1728;
  int t = bid - lay * 1728;
  int lsrc = l0 + lay;
  __hip_bfloat16* ob = out + (size_t)lay * WSLAB_;
  const float* src; __hip_bfloat16* dst;
  int K, Nn, ntk;
  if (t < 576) {
    int which = t / 144; t -= which * 144;
    K = E_; Nn = E_; ntk = 12;
    if (which == 0)      { src = wq + (size_t)lsrc * E_ * E_; dst = ob + OFF_QKV_; }
    else if (which == 1) { src = wk + (size_t)lsrc * E_ * E_; dst = ob + OFF_QKV_ + (size_t)E_ * E_; }
    else if (which == 2) { src = wv + (size_t)lsrc * E_ * E_; dst = ob + OFF_QKV_ + (size_t)2 * E_ * E_; }
    else                 { src = wo + (size_t)lsrc * E_ * E_; dst = ob + OFF_WO_; }
  } else if (t < 1152) {
    t -= 576; K = E_; Nn = FF_; ntk = 12;
    src = w1 + (size_t)lsrc * E_ * FF_; dst = ob + OFF_W1_;
  } else {
    t -= 1152; K = FF_; Nn = E_; ntk = 48;
    src = w2 + (size_t)lsrc * FF_ * E_; dst = ob + OFF_W2_;
  }
  int kt = t % ntk, nt = t / ntk;
  int k0 = kt * 64, n0 = nt * 64;
  __shared__ float tt[64][65];
  int tid = threadIdx.x;
  int c = tid & 63, rg = tid >> 6;
#pragma unroll
  for (int i = 0; i < 16; ++i) {
    int r = rg * 16 + i;
    tt[r][c] = src[(size_t)(k0 + r) * Nn + n0 + c];
  }
  __syncthreads();
#pragma unroll
  for (int i = 0; i < 16; ++i) {
    int ro = rg * 16 + i;
    dst[(size_t)(n0 + ro) * K + (k0 + c)] = __float2bfloat16(tt[c][ro]);
  }
}

// ---------------- MFMA GEMM: C[128 x BN per block] = A[M,K] @ Bt[Npad,K]^T ----------------
// BK=64 (128B LDS rows), 4 waves. Both-sides row-XOR swizzle (rule 21):
// linear LDS dest; source chunk = (l&7)^(l>>3); read chunk = ((hf*4+kg)^(lr&7)).
// -> each bank serves exactly 8 accesses per ds_read_b128 = the b128 floor (conflict-free).
// flags&1: GELU. flags&2 (BN=128): head path, LDS-transposed coalesced nt stores.
// nrt>0: 1-D launch, XCD-chunked column-panel-major remap.
template<int BN>
__global__ __launch_bounds__(256) void gemm_bt_kernel(
    const __hip_bfloat16* __restrict__ A, const __hip_bfloat16* __restrict__ Bt,
    const float* __restrict__ bias, const float* __restrict__ R,
    float* __restrict__ Cf, __hip_bfloat16* __restrict__ Cb,
    __hip_bfloat16* __restrict__ vt,
    int Nn, int K, int flags, int nrt) {
  constexpr int NROWS = 128 + BN;
  __shared__ __align__(16) unsigned short SM[NROWS * 64];   // rows of 64 shorts (128B)
  unsigned short* As = SM;
  unsigned short* Bs = SM + 128 * 64;
  int tid = threadIdx.x;
  int w = tid >> 6, l = tid & 63;
  constexpr int MF  = (BN == 128) ? 4 : 2;    // m-fragments per wave
  constexpr int WRT = (BN == 128) ? 64 : 32;  // wave row-tile
  int wr = (BN == 128) ? (w >> 1) : w;
  int wc = (BN == 128) ? (w & 1) : 0;
  int bx, by;
  if (nrt > 0) {
    int bid = blockIdx.x;
    int q = gridDim.x >> 3;
    int nb = (bid & 7) * q + (bid >> 3);
    bx = nb / nrt; by = nb - bx * nrt;
  } else { bx = blockIdx.x; by = blockIdx.y; }
  int row0 = by * 128, col0 = bx * BN;
  int lr = l & 15, kg = l >> 4;
  const unsigned short* Ag = (const unsigned short*)A;
  const unsigned short* Bg = (const unsigned short*)Bt;
  int srow = l >> 3;                 // 0..7 within 8-row staging group
  int schunk = (l & 7) ^ srow;       // pre-swizzled source 16B-chunk (0..7)

  f32x4 acc[MF][4];
#pragma unroll
  for (int m = 0; m < MF; ++m)
#pragma unroll
    for (int n = 0; n < 4; ++n) acc[m][n] = (f32x4){0.f, 0.f, 0.f, 0.f};

  constexpr int NS = NROWS / 32;     // staging rounds (8 rows per wave-instr, 4 waves)
  for (int k0 = 0; k0 < K; k0 += 64) {
#pragma unroll
    for (int s = 0; s < NS; ++s) {
      int idx8 = s * 4 + w;          // 8-row block index, wave-uniform
      if (idx8 < 16)
        async_ld16(Ag + (size_t)(row0 + idx8 * 8 + srow) * K + k0 + schunk * 8,
                   &As[idx8 * 8 * 64]);
      else
        async_ld16(Bg + (size_t)(col0 + (idx8 - 16) * 8 + srow) * K + k0 + schunk * 8,
                   &Bs[(idx8 - 16) * 8 * 64]);
    }
    __syncthreads();
#pragma unroll
    for (int hf = 0; hf < 2; ++hf) {
      short8 af[MF], bf[4];
#pragma unroll
      for (int m = 0; m < MF; ++m) {
        int r = wr * WRT + m * 16 + lr;
        af[m] = *(const short8*)&As[r * 64 + ((((hf << 2) | kg)) ^ (lr & 7)) * 8];
      }
#pragma unroll
      for (int n = 0; n < 4; ++n) {
        int r = wc * 64 + n * 16 + lr;
        bf[n] = *(const short8*)&Bs[r * 64 + ((((hf << 2) | kg)) ^ (lr & 7)) * 8];
      }
#pragma unroll
      for (int m = 0; m < MF; ++m)
#pragma unroll
        for (int n = 0; n < 4; ++n)
          acc[m][n] = __builtin_amdgcn_mfma_f32_16x16x32_bf16(af[m], bf[n], acc[m][n], 0, 0, 0);
    }
    __syncthreads();
  }

  if constexpr (BN == 128) {
    if (flags & 2) {
      // head epilogue: LDS-transpose 32 rows/pass, coalesced nt stores.
      // bank fix: col ^= 16*(kg&1) on write; read undoes with 16*((r>>2)&1).
      float* Ls = (float*)SM;   // 32 x 128 fp32 = 16 KB (SM is 32 KB)
      bool nfull = (col0 + 128 <= Nn);
#pragma unroll
      for (int p = 0; p < 4; ++p) {
        __syncthreads();
        if (wr == (p >> 1)) {
          int mb = (p & 1) * 2;
#pragma unroll
          for (int m2 = 0; m2 < 2; ++m2)
#pragma unroll
            for (int n = 0; n < 4; ++n)
#pragma unroll
              for (int j = 0; j < 4; ++j)
                Ls[(m2 * 16 + kg * 4 + j) * 128 + ((wc * 64 + n * 16 + lr) ^ (16 * (kg & 1)))]
                    = acc[mb + m2][n][j];
        }
        __syncthreads();
        int rbase = row0 + p * 32;
        if (nfull) {
#pragma unroll
          for (int i = 0; i < 16; ++i) {
            int idx = i * 256 + tid;
            int r = idx >> 7, c = idx & 127;
            float v = Ls[r * 128 + (c ^ (16 * ((r >> 2) & 1)))];
            __builtin_nontemporal_store(v, &Cf[(size_t)(rbase + r) * Nn + col0 + c]);
          }
        } else {
          for (int i = 0; i < 16; ++i) {
            int idx = i * 256 + tid;
            int r = idx >> 7, c = idx & 127;
            if (col0 + c < Nn) {
              float v = Ls[r * 128 + (c ^ (16 * ((r >> 2) & 1)))];
              __builtin_nontemporal_store(v, &Cf[(size_t)(rbase + r) * Nn + col0 + c]);
            }
          }
        }
      }
      return;
    }
  }

  unsigned short* vtb = (unsigned short*)vt;
#pragma unroll
  for (int n = 0; n < 4; ++n) {
    int col = col0 + wc * 64 + n * 16 + lr;
    if (col >= Nn) continue;
    float bv = bias ? bias[col] : 0.f;
    bool to_vt = (vtb != nullptr) && (col >= 2 * E_);
    int hh = 0, dd = 0;
    if (to_vt) { int c2 = col - 2 * E_; hh = c2 >> 6; dd = c2 & 63; }
#pragma unroll
    for (int m = 0; m < MF; ++m) {
#pragma unroll
      for (int j = 0; j < 4; ++j) {
        int row = row0 + wr * WRT + m * 16 + kg * 4 + j;
        float val = acc[m][n][j] + bv;
        if (flags & 1) val = gelu_f(val);
        if (R) val += R[(size_t)row * Nn + col];
        if (Cf) Cf[(size_t)row * Nn + col] = val;
        if (to_vt) {
          int bz = row >> 10, nn = row & (N_ - 1);
          vtb[((size_t)(bz * H_ + hh) * HD_ + dd) * N_ + nn] = f2bf(val);
        } else if (Cb) {
          Cb[(size_t)row * Nn + col] = __float2bfloat16(val);
        }
      }
    }
  }
}

// ---------------- flash attention: 1 wave/block, 16 q-rows, 32-key steps ----------------
#define PRS_ 40
__global__ __launch_bounds__(64) void fattn_kernel(
    const __hip_bfloat16* __restrict__ qkv, const __hip_bfloat16* __restrict__ vt,
    __hip_bfloat16* __restrict__ o) {
  int qt = blockIdx.x, hh = blockIdx.y, bz = blockIdx.z;
  int q0 = qt * 16;
  int l = threadIdx.x;
  int lr = l & 15, kg = l >> 4;
  const unsigned short* base = (const unsigned short*)qkv;
  const unsigned short* vtb = (const unsigned short*)vt + ((size_t)(bz * H_ + hh)) * HD_ * N_;
  __shared__ __align__(16) unsigned short P[16 * PRS_];

  short8 qf[2];
  const unsigned short* qrow = base + (size_t)(bz * N_ + q0 + lr) * QKVW_ + hh * HD_;
#pragma unroll
  for (int c = 0; c < 2; ++c) qf[c] = *(const short8*)(qrow + c * 32 + kg * 8);

  float mrow[4], lsum[4];
  f32x4 accO[4];
#pragma unroll
  for (int j = 0; j < 4; ++j) { mrow[j] = -INFINITY; lsum[j] = 0.f; }
#pragma unroll
  for (int db = 0; db < 4; ++db) accO[db] = (f32x4){0.f, 0.f, 0.f, 0.f};

  int nsteps = (q0 + 16 + 31) / 32;
  for (int kt = 0; kt < nsteps; ++kt) {
    f32x4 s[2];
#pragma unroll
    for (int t = 0; t < 2; ++t) {
      const unsigned short* krow = base + (size_t)(bz * N_ + kt * 32 + t * 16 + lr) * QKVW_ + E_ + hh * HD_;
      short8 kf0 = *(const short8*)(krow + kg * 8);
      short8 kf1 = *(const short8*)(krow + 32 + kg * 8);
      f32x4 acc = (f32x4){0.f, 0.f, 0.f, 0.f};
      acc = __builtin_amdgcn_mfma_f32_16x16x32_bf16(qf[0], kf0, acc, 0, 0, 0);
      acc = __builtin_amdgcn_mfma_f32_16x16x32_bf16(qf[1], kf1, acc, 0, 0, 0);
      s[t] = acc;
    }
    float pm[2][4];
#pragma unroll
    for (int t = 0; t < 2; ++t) {
      int kglob = kt * 32 + t * 16 + lr;
#pragma unroll
      for (int j = 0; j < 4; ++j) {
        int qglob = q0 + kg * 4 + j;
        pm[t][j] = (kglob <= qglob) ? s[t][j] * 0.125f : -INFINITY;
      }
    }
#pragma unroll
    for (int j = 0; j < 4; ++j) {
      float tm = fmaxf(pm[0][j], pm[1][j]);
      tm = fmaxf(tm, __shfl_xor(tm, 1));
      tm = fmaxf(tm, __shfl_xor(tm, 2));
      tm = fmaxf(tm, __shfl_xor(tm, 4));
      tm = fmaxf(tm, __shfl_xor(tm, 8));
      float mnew = fmaxf(mrow[j], tm);
      float alpha = __expf(mrow[j] - mnew);
      float p0 = __expf(pm[0][j] - mnew);
      float p1 = __expf(pm[1][j] - mnew);
      float rs = p0 + p1;
      rs += __shfl_xor(rs, 1);
      rs += __shfl_xor(rs, 2);
      rs += __shfl_xor(rs, 4);
      rs += __shfl_xor(rs, 8);
      lsum[j] = lsum[j] * alpha + rs;
      mrow[j] = mnew;
#pragma unroll
      for (int db = 0; db < 4; ++db) accO[db][j] *= alpha;
      P[(kg * 4 + j) * PRS_ + lr]      = f2bf(p0);
      P[(kg * 4 + j) * PRS_ + 16 + lr] = f2bf(p1);
    }
    __syncthreads();
    short8 pa = *(const short8*)&P[lr * PRS_ + kg * 8];
#pragma unroll
    for (int db = 0; db < 4; ++db) {
      short8 vf = *(const short8*)(vtb + (size_t)(db * 16 + lr) * N_ + kt * 32 + kg * 8);
      accO[db] = __builtin_amdgcn_mfma_f32_16x16x32_bf16(pa, vf, accO[db], 0, 0, 0);
    }
    __syncthreads();
  }
  unsigned short* ob = (unsigned short*)o;
#pragma unroll
  for (int j = 0; j < 4; ++j) {
    float inv = 1.f / lsum[j];
    size_t orow = (size_t)(bz * N_ + q0 + kg * 4 + j) * E_ + hh * HD_;
#pragma unroll
    for (int db = 0; db < 4; ++db)
      ob[orow + db * 16 + lr] = f2bf(accO[db][j] * inv);
  }
}

extern "C" void kernel_launch(void* const* d_in, const int* in_sizes, int n_in,
                              void* d_out, int out_size, void* d_ws, size_t ws_size,
                              hipStream_t stream) {
  const int*   x     = (const int*)  d_in[0];
  const float* tok   = (const float*)d_in[1];
  const float* wq    = (const float*)d_in[2];
  const float* wk    = (const float*)d_in[3];
  const float* wv    = (const float*)d_in[4];
  const float* wo    = (const float*)d_in[5];
  const float* bo    = (const float*)d_in[6];
  const float* ln1g  = (const float*)d_in[7];
  const float* ln1b  = (const float*)d_in[8];
  const float* ln2g  = (const float*)d_in[9];
  const float* ln2b  = (const float*)d_in[10];
  const float* w1    = (const float*)d_in[11];
  const float* b1    = (const float*)d_in[12];
  const float* w2    = (const float*)d_in[13];
  const float* b2    = (const float*)d_in[14];
  const float* lnfg  = (const float*)d_in[15];
  const float* lnfb  = (const float*)d_in[16];
  const float* whead = (const float*)d_in[17];
  float* out = (float*)d_out;

  char* wsb = (char*)d_ws;
  size_t off = 0;
  auto alloc = [&](size_t bytes) -> void* {
    void* p = wsb + off; off += (bytes + 255) & ~(size_t)255; return p;
  };
  float*           h        = (float*)          alloc((size_t)M_ * E_ * 4);
  __hip_bfloat16*  y_bf     = (__hip_bfloat16*) alloc((size_t)M_ * E_ * 2);
  __hip_bfloat16*  qkv_bf   = (__hip_bfloat16*) alloc((size_t)M_ * QKVW_ * 2);
  __hip_bfloat16*  vt_bf    = (__hip_bfloat16*) alloc((size_t)B_ * H_ * HD_ * N_ * 2);
  __hip_bfloat16*  o_bf     = (__hip_bfloat16*) alloc((size_t)M_ * E_ * 2);
  __hip_bfloat16*  mid_bf   = (__hip_bfloat16*) alloc((size_t)M_ * FF_ * 2);
  __hip_bfloat16*  whead_bt = (__hip_bfloat16*) alloc((size_t)VPAD_ * E_ * 2);
  bool preall = (off + (size_t)6 * WSLAB_ * 2 <= ws_size);
  __hip_bfloat16* wslab = (__hip_bfloat16*) alloc(((size_t)(preall ? 6 : 1)) * WSLAB_ * 2);

  dim3 blk(256);

  embed_kernel<<<(B_ * N_ * E_ + 255) / 256, blk, 0, stream>>>(x, tok, h);
  transpose_cast_kernel<<<dim3(E_ / 64, VPAD_ / 64), blk, 0, stream>>>(whead, whead_bt, E_, V_);
  if (preall)
    wtrans_kernel<<<6 * 1728, blk, 0, stream>>>(wq, wk, wv, wo, w1, w2, wslab, 0);

  dim3 gqkv(QKVW_ / 128, M_ / 128);
  dim3 gffn1(FF_ / 128, M_ / 128);
  dim3 g64(E_ / 64, M_ / 128);
  dim3 gfa(N_ / 16, H_, B_);

  for (int l = 0; l < L_; ++l) {
    if (!preall)
      wtrans_kernel<<<1728, blk, 0, stream>>>(wq, wk, wv, wo, w1, w2, wslab, l);
    __hip_bfloat16* wb = wslab + (preall ? (size_t)l * WSLAB_ : 0);

    layernorm_kernel<<<M_, blk, 0, stream>>>(h, y_bf, ln1g + (size_t)l * E_, ln1b + (size_t)l * E_);
    gemm_bt_kernel<128><<<gqkv, blk, 0, stream>>>(y_bf, wb + OFF_QKV_, nullptr, nullptr,
        nullptr, qkv_bf, vt_bf, QKVW_, E_, 0, 0);
    fattn_kernel<<<gfa, dim3(64), 0, stream>>>(qkv_bf, vt_bf, o_bf);
    gemm_bt_kernel<64><<<g64, blk, 0, stream>>>(o_bf, wb + OFF_WO_, bo + (size_t)l * E_, h,
        h, nullptr, nullptr, E_, E_, 0, 0);
    layernorm_kernel<<<M_, blk, 0, stream>>>(h, y_bf, ln2g + (size_t)l * E_, ln2b + (size_t)l * E_);
    gemm_bt_kernel<128><<<gffn1, blk, 0, stream>>>(y_bf, wb + OFF_W1_, b1 + (size_t)l * FF_,
        nullptr, nullptr, mid_bf, nullptr, FF_, E_, 1, 0);
    gemm_bt_kernel<64><<<g64, blk, 0, stream>>>(mid_bf, wb + OFF_W2_, b2 + (size_t)l * E_, h,
        h, nullptr, nullptr, E_, FF_, 0, 0);
  }

  layernorm_kernel<<<M_, blk, 0, stream>>>(h, y_bf, lnfg, lnfb);
  gemm_bt_kernel<128><<<dim3((VPAD_ / 128) * (M_ / 128)), blk, 0, stream>>>(
      y_bf, whead_bt, nullptr, nullptr, out, nullptr, nullptr, V_, E_, 2, M_ / 128);
}

// Round 7
// 1435.568 us; speedup vs baseline: 9.5337x; 1.0902x over previous
//
#include <hip/hip_runtime.h>
#include <hip/hip_bf16.h>
#include <math.h>

#define B_  2
#define N_  1024
#define E_  768
#define H_  12
#define HD_ 64
#define L_  6
#define FF_ 3072
#define V_  50257
#define VPAD_ 50304
#define QKVW_ 2304
#define M_  (B_ * N_)   // 2048

// per-layer transposed-weight slab (bf16 element offsets)
#define OFF_QKV_ 0
#define OFF_WO_  (QKVW_ * E_)
#define OFF_W1_  (OFF_WO_ + E_ * E_)
#define OFF_W2_  (OFF_W1_ + FF_ * E_)
#define WSLAB_   ((size_t)(OFF_W2_ + E_ * FF_))   // 7077888 elems

typedef short short8 __attribute__((ext_vector_type(8)));
typedef float f32x4 __attribute__((ext_vector_type(4)));

__device__ __forceinline__ float gelu_f(float x) {
  return 0.5f * x * (1.0f + tanhf(0.7978845608028654f * (x + 0.044715f * x * x * x)));
}

__device__ __forceinline__ unsigned short f2bf(float f) {
  __hip_bfloat16 b = __float2bfloat16(f);
  return *reinterpret_cast<unsigned short*>(&b);
}

__device__ __forceinline__ void async_ld16(const void* g, void* l) {
  __builtin_amdgcn_global_load_lds(
      (const __attribute__((address_space(1))) void*)g,
      (__attribute__((address_space(3))) void*)l, 16, 0, 0);
}

// ---------------- embed ----------------
__global__ __launch_bounds__(256) void embed_kernel(const int* __restrict__ x,
    const float* __restrict__ tok, float* __restrict__ h) {
  int idx = blockIdx.x * 256 + threadIdx.x;
  const int total = B_ * N_ * E_;
  if (idx >= total) return;
  int e  = idx % E_;
  int bn = idx / E_;
  int n  = bn % N_;
  int t  = x[bn];
  float freq = expf(-9.210340371976184f * (float)(2 * e) / (float)E_);
  float arg  = (float)n * freq;
  float pe   = (e & 1) ? cosf(arg) : sinf(arg);
  h[idx] = tok[(size_t)t * E_ + e] + pe;
}

// ---------------- layernorm: fp32 in -> bf16 out ----------------
__global__ __launch_bounds__(256) void layernorm_kernel(const float* __restrict__ in,
    __hip_bfloat16* __restrict__ out, const float* __restrict__ g, const float* __restrict__ b) {
  int row = blockIdx.x;
  const float* xr = in + (size_t)row * E_;
  __shared__ float red[256];
  int tid = threadIdx.x;
  float s = 0.f, ss = 0.f;
  for (int e = tid; e < E_; e += 256) { float v = xr[e]; s += v; ss += v * v; }
  red[tid] = s; __syncthreads();
  for (int o = 128; o > 0; o >>= 1) { if (tid < o) red[tid] += red[tid + o]; __syncthreads(); }
  float mean = red[0] / (float)E_;
  __syncthreads();
  red[tid] = ss; __syncthreads();
  for (int o = 128; o > 0; o >>= 1) { if (tid < o) red[tid] += red[tid + o]; __syncthreads(); }
  float var = red[0] / (float)E_ - mean * mean;
  float inv = rsqrtf(var + 1e-5f);
  for (int e = tid; e < E_; e += 256)
    out[(size_t)row * E_ + e] = __float2bfloat16(g[e] * (xr[e] - mean) * inv + b[e]);
}

// ---------------- transpose + cast (head weight) ----------------
__global__ __launch_bounds__(256) void transpose_cast_kernel(const float* __restrict__ in,
    __hip_bfloat16* __restrict__ out, int K, int Nn) {
  __shared__ float t[64][65];
  int k0 = blockIdx.x * 64, n0 = blockIdx.y * 64;
  int tid = threadIdx.x;
  int c = tid & 63, rg = tid >> 6;
#pragma unroll
  for (int i = 0; i < 16; ++i) {
    int r = rg * 16 + i;
    int n = n0 + c;
    t[r][c] = (n < Nn) ? in[(size_t)(k0 + r) * Nn + n] : 0.0f;
  }
  __syncthreads();
#pragma unroll
  for (int i = 0; i < 16; ++i) {
    int ro = rg * 16 + i;
    out[(size_t)(n0 + ro) * K + (k0 + c)] = __float2bfloat16(t[c][ro]);
  }
}

// ---------------- per-layer weight transposes, nl layers in one launch ----------------
__global__ __launch_bounds__(256) void wtrans_kernel(
    const float* __restrict__ wq, const float* __restrict__ wk,
    const float* __restrict__ wv, const float* __restrict__ wo,
    const float* __restrict__ w1, const float* __restrict__ w2,
    __hip_bfloat16* __restrict__ out, int l0) {
  int bid = blockIdx.x;
  int lay = bid / 1728;
  int t = bid - lay * 1728;
  int lsrc = l0 + lay;
  __hip_bfloat16* ob = out + (size_t)lay * WSLAB_;
  const float* src; __hip_bfloat16* dst;
  int K, Nn, ntk;
  if (t < 576) {
    int which = t / 144; t -= which * 144;
    K = E_; Nn = E_; ntk = 12;
    if (which == 0)      { src = wq + (size_t)lsrc * E_ * E_; dst = ob + OFF_QKV_; }
    else if (which == 1) { src = wk + (size_t)lsrc * E_ * E_; dst = ob + OFF_QKV_ + (size_t)E_ * E_; }
    else if (which == 2) { src = wv + (size_t)lsrc * E_ * E_; dst = ob + OFF_QKV_ + (size_t)2 * E_ * E_; }
    else                 { src = wo + (size_t)lsrc * E_ * E_; dst = ob + OFF_WO_; }
  } else if (t < 1152) {
    t -= 576; K = E_; Nn = FF_; ntk = 12;
    src = w1 + (size_t)lsrc * E_ * FF_; dst = ob + OFF_W1_;
  } else {
    t -= 1152; K = FF_; Nn = E_; ntk = 48;
    src = w2 + (size_t)lsrc * FF_ * E_; dst = ob + OFF_W2_;
  }
  int kt = t % ntk, nt = t / ntk;
  int k0 = kt * 64, n0 = nt * 64;
  __shared__ float tt[64][65];
  int tid = threadIdx.x;
  int c = tid & 63, rg = tid >> 6;
#pragma unroll
  for (int i = 0; i < 16; ++i) {
    int r = rg * 16 + i;
    tt[r][c] = src[(size_t)(k0 + r) * Nn + n0 + c];
  }
  __syncthreads();
#pragma unroll
  for (int i = 0; i < 16; ++i) {
    int ro = rg * 16 + i;
    dst[(size_t)(n0 + ro) * K + (k0 + c)] = __float2bfloat16(tt[c][ro]);
  }
}

// ---------------- MFMA GEMM: C[128 x BN per block] = A[M,K] @ Bt[Npad,K]^T ----------------
// BK=64 rows (128B), 4 waves, conflict-free row-XOR swizzle (verified r6: conflicts=0).
// T3 2-phase double-buffer: issue STAGE(t+1) -> ds_read+MFMA(t) -> ONE barrier per K-step.
// MFMA execution sits between load-issue and the barrier's vmcnt drain -> latency hidden.
// flags&1: GELU. flags&2 (BN=128): head path, LDS-transposed coalesced nt stores.
// nrt>0: 1-D launch, XCD-chunked column-panel-major remap.
template<int BN>
__global__ __launch_bounds__(256) void gemm_bt_kernel(
    const __hip_bfloat16* __restrict__ A, const __hip_bfloat16* __restrict__ Bt,
    const float* __restrict__ bias, const float* __restrict__ R,
    float* __restrict__ Cf, __hip_bfloat16* __restrict__ Cb,
    __hip_bfloat16* __restrict__ vt,
    int Nn, int K, int flags, int nrt) {
  constexpr int NROWS = 128 + BN;
  __shared__ __align__(16) unsigned short SM[2 * NROWS * 64];  // double-buffered
  int tid = threadIdx.x;
  int w = tid >> 6, l = tid & 63;
  constexpr int MF  = (BN == 128) ? 4 : 2;    // m-fragments per wave
  constexpr int WRT = (BN == 128) ? 64 : 32;  // wave row-tile
  int wr = (BN == 128) ? (w >> 1) : w;
  int wc = (BN == 128) ? (w & 1) : 0;
  int bx, by;
  if (nrt > 0) {
    int bid = blockIdx.x;
    int q = gridDim.x >> 3;
    int nb = (bid & 7) * q + (bid >> 3);
    bx = nb / nrt; by = nb - bx * nrt;
  } else { bx = blockIdx.x; by = blockIdx.y; }
  int row0 = by * 128, col0 = bx * BN;
  int lr = l & 15, kg = l >> 4;
  const unsigned short* Ag = (const unsigned short*)A;
  const unsigned short* Bg = (const unsigned short*)Bt;
  int srow = l >> 3;                 // 0..7 within 8-row staging group
  int schunk = (l & 7) ^ srow;       // pre-swizzled source 16B-chunk (0..7)

  constexpr int NS = NROWS / 32;     // staging rounds (8 rows per wave-instr, 4 waves)
  auto stage = [&](int buf, int k0) {
    unsigned short* As = SM + buf * (NROWS * 64);
    unsigned short* Bs = As + 128 * 64;
#pragma unroll
    for (int s = 0; s < NS; ++s) {
      int idx8 = s * 4 + w;          // 8-row block index, wave-uniform
      if (idx8 < 16)
        async_ld16(Ag + (size_t)(row0 + idx8 * 8 + srow) * K + k0 + schunk * 8,
                   &As[idx8 * 8 * 64]);
      else
        async_ld16(Bg + (size_t)(col0 + (idx8 - 16) * 8 + srow) * K + k0 + schunk * 8,
                   &Bs[(idx8 - 16) * 8 * 64]);
    }
  };

  f32x4 acc[MF][4];
#pragma unroll
  for (int m = 0; m < MF; ++m)
#pragma unroll
    for (int n = 0; n < 4; ++n) acc[m][n] = (f32x4){0.f, 0.f, 0.f, 0.f};

  int nt = K >> 6;
  stage(0, 0);
  __syncthreads();                   // drain: buf0 ready
  int cur = 0;
  for (int t = 0; t < nt; ++t) {
    if (t + 1 < nt) stage(cur ^ 1, (t + 1) << 6);   // issue next tile first
    const unsigned short* As = SM + cur * (NROWS * 64);
    const unsigned short* Bs = As + 128 * 64;
#pragma unroll
    for (int hf = 0; hf < 2; ++hf) {
      short8 af[MF], bf[4];
#pragma unroll
      for (int m = 0; m < MF; ++m) {
        int r = wr * WRT + m * 16 + lr;
        af[m] = *(const short8*)&As[r * 64 + ((((hf << 2) | kg)) ^ (lr & 7)) * 8];
      }
#pragma unroll
      for (int n = 0; n < 4; ++n) {
        int r = wc * 64 + n * 16 + lr;
        bf[n] = *(const short8*)&Bs[r * 64 + ((((hf << 2) | kg)) ^ (lr & 7)) * 8];
      }
#pragma unroll
      for (int m = 0; m < MF; ++m)
#pragma unroll
        for (int n = 0; n < 4; ++n)
          acc[m][n] = __builtin_amdgcn_mfma_f32_16x16x32_bf16(af[m], bf[n], acc[m][n], 0, 0, 0);
    }
    if (t + 1 < nt) { __syncthreads(); cur ^= 1; }  // drain next tile; protect old buf
  }

  if constexpr (BN == 128) {
    if (flags & 2) {
      // head epilogue: LDS-transpose 32 rows/pass, coalesced nt stores.
      float* Ls = (float*)SM;   // 16 KB of the 64 KB
      bool nfull = (col0 + 128 <= Nn);
#pragma unroll
      for (int p = 0; p < 4; ++p) {
        __syncthreads();
        if (wr == (p >> 1)) {
          int mb = (p & 1) * 2;
#pragma unroll
          for (int m2 = 0; m2 < 2; ++m2)
#pragma unroll
            for (int n = 0; n < 4; ++n)
#pragma unroll
              for (int j = 0; j < 4; ++j)
                Ls[(m2 * 16 + kg * 4 + j) * 128 + ((wc * 64 + n * 16 + lr) ^ (16 * (kg & 1)))]
                    = acc[mb + m2][n][j];
        }
        __syncthreads();
        int rbase = row0 + p * 32;
        if (nfull) {
#pragma unroll
          for (int i = 0; i < 16; ++i) {
            int idx = i * 256 + tid;
            int r = idx >> 7, c = idx & 127;
            float v = Ls[r * 128 + (c ^ (16 * ((r >> 2) & 1)))];
            __builtin_nontemporal_store(v, &Cf[(size_t)(rbase + r) * Nn + col0 + c]);
          }
        } else {
          for (int i = 0; i < 16; ++i) {
            int idx = i * 256 + tid;
            int r = idx >> 7, c = idx & 127;
            if (col0 + c < Nn) {
              float v = Ls[r * 128 + (c ^ (16 * ((r >> 2) & 1)))];
              __builtin_nontemporal_store(v, &Cf[(size_t)(rbase + r) * Nn + col0 + c]);
            }
          }
        }
      }
      return;
    }
  }

  unsigned short* vtb = (unsigned short*)vt;
#pragma unroll
  for (int n = 0; n < 4; ++n) {
    int col = col0 + wc * 64 + n * 16 + lr;
    if (col >= Nn) continue;
    float bv = bias ? bias[col] : 0.f;
    bool to_vt = (vtb != nullptr) && (col >= 2 * E_);
    int hh = 0, dd = 0;
    if (to_vt) { int c2 = col - 2 * E_; hh = c2 >> 6; dd = c2 & 63; }
#pragma unroll
    for (int m = 0; m < MF; ++m) {
#pragma unroll
      for (int j = 0; j < 4; ++j) {
        int row = row0 + wr * WRT + m * 16 + kg * 4 + j;
        float val = acc[m][n][j] + bv;
        if (flags & 1) val = gelu_f(val);
        if (R) val += R[(size_t)row * Nn + col];
        if (Cf) Cf[(size_t)row * Nn + col] = val;
        if (to_vt) {
          int bz = row >> 10, nn = row & (N_ - 1);
          vtb[((size_t)(bz * H_ + hh) * HD_ + dd) * N_ + nn] = f2bf(val);
        } else if (Cb) {
          Cb[(size_t)row * Nn + col] = __float2bfloat16(val);
        }
      }
    }
  }
}

// ---------------- flash attention: 1 wave/block, 16 q-rows, 32-key steps ----------------
#define PRS_ 40
__global__ __launch_bounds__(64) void fattn_kernel(
    const __hip_bfloat16* __restrict__ qkv, const __hip_bfloat16* __restrict__ vt,
    __hip_bfloat16* __restrict__ o) {
  int qt = blockIdx.x, hh = blockIdx.y, bz = blockIdx.z;
  int q0 = qt * 16;
  int l = threadIdx.x;
  int lr = l & 15, kg = l >> 4;
  const unsigned short* base = (const unsigned short*)qkv;
  const unsigned short* vtb = (const unsigned short*)vt + ((size_t)(bz * H_ + hh)) * HD_ * N_;
  __shared__ __align__(16) unsigned short P[16 * PRS_];

  short8 qf[2];
  const unsigned short* qrow = base + (size_t)(bz * N_ + q0 + lr) * QKVW_ + hh * HD_;
#pragma unroll
  for (int c = 0; c < 2; ++c) qf[c] = *(const short8*)(qrow + c * 32 + kg * 8);

  float mrow[4], lsum[4];
  f32x4 accO[4];
#pragma unroll
  for (int j = 0; j < 4; ++j) { mrow[j] = -INFINITY; lsum[j] = 0.f; }
#pragma unroll
  for (int db = 0; db < 4; ++db) accO[db] = (f32x4){0.f, 0.f, 0.f, 0.f};

  int nsteps = (q0 + 16 + 31) / 32;
  for (int kt = 0; kt < nsteps; ++kt) {
    f32x4 s[2];
#pragma unroll
    for (int t = 0; t < 2; ++t) {
      const unsigned short* krow = base + (size_t)(bz * N_ + kt * 32 + t * 16 + lr) * QKVW_ + E_ + hh * HD_;
      short8 kf0 = *(const short8*)(krow + kg * 8);
      short8 kf1 = *(const short8*)(krow + 32 + kg * 8);
      f32x4 acc = (f32x4){0.f, 0.f, 0.f, 0.f};
      acc = __builtin_amdgcn_mfma_f32_16x16x32_bf16(qf[0], kf0, acc, 0, 0, 0);
      acc = __builtin_amdgcn_mfma_f32_16x16x32_bf16(qf[1], kf1, acc, 0, 0, 0);
      s[t] = acc;
    }
    float pm[2][4];
#pragma unroll
    for (int t = 0; t < 2; ++t) {
      int kglob = kt * 32 + t * 16 + lr;
#pragma unroll
      for (int j = 0; j < 4; ++j) {
        int qglob = q0 + kg * 4 + j;
        pm[t][j] = (kglob <= qglob) ? s[t][j] * 0.125f : -INFINITY;
      }
    }
#pragma unroll
    for (int j = 0; j < 4; ++j) {
      float tm = fmaxf(pm[0][j], pm[1][j]);
      tm = fmaxf(tm, __shfl_xor(tm, 1));
      tm = fmaxf(tm, __shfl_xor(tm, 2));
      tm = fmaxf(tm, __shfl_xor(tm, 4));
      tm = fmaxf(tm, __shfl_xor(tm, 8));
      float mnew = fmaxf(mrow[j], tm);
      float alpha = __expf(mrow[j] - mnew);
      float p0 = __expf(pm[0][j] - mnew);
      float p1 = __expf(pm[1][j] - mnew);
      float rs = p0 + p1;
      rs += __shfl_xor(rs, 1);
      rs += __shfl_xor(rs, 2);
      rs += __shfl_xor(rs, 4);
      rs += __shfl_xor(rs, 8);
      lsum[j] = lsum[j] * alpha + rs;
      mrow[j] = mnew;
#pragma unroll
      for (int db = 0; db < 4; ++db) accO[db][j] *= alpha;
      P[(kg * 4 + j) * PRS_ + lr]      = f2bf(p0);
      P[(kg * 4 + j) * PRS_ + 16 + lr] = f2bf(p1);
    }
    __syncthreads();
    short8 pa = *(const short8*)&P[lr * PRS_ + kg * 8];
#pragma unroll
    for (int db = 0; db < 4; ++db) {
      short8 vf = *(const short8*)(vtb + (size_t)(db * 16 + lr) * N_ + kt * 32 + kg * 8);
      accO[db] = __builtin_amdgcn_mfma_f32_16x16x32_bf16(pa, vf, accO[db], 0, 0, 0);
    }
    __syncthreads();
  }
  unsigned short* ob = (unsigned short*)o;
#pragma unroll
  for (int j = 0; j < 4; ++j) {
    float inv = 1.f / lsum[j];
    size_t orow = (size_t)(bz * N_ + q0 + kg * 4 + j) * E_ + hh * HD_;
#pragma unroll
    for (int db = 0; db < 4; ++db)
      ob[orow + db * 16 + lr] = f2bf(accO[db][j] * inv);
  }
}

extern "C" void kernel_launch(void* const* d_in, const int* in_sizes, int n_in,
                              void* d_out, int out_size, void* d_ws, size_t ws_size,
                              hipStream_t stream) {
  const int*   x     = (const int*)  d_in[0];
  const float* tok   = (const float*)d_in[1];
  const float* wq    = (const float*)d_in[2];
  const float* wk    = (const float*)d_in[3];
  const float* wv    = (const float*)d_in[4];
  const float* wo    = (const float*)d_in[5];
  const float* bo    = (const float*)d_in[6];
  const float* ln1g  = (const float*)d_in[7];
  const float* ln1b  = (const float*)d_in[8];
  const float* ln2g  = (const float*)d_in[9];
  const float* ln2b  = (const float*)d_in[10];
  const float* w1    = (const float*)d_in[11];
  const float* b1    = (const float*)d_in[12];
  const float* w2    = (const float*)d_in[13];
  const float* b2    = (const float*)d_in[14];
  const float* lnfg  = (const float*)d_in[15];
  const float* lnfb  = (const float*)d_in[16];
  const float* whead = (const float*)d_in[17];
  float* out = (float*)d_out;

  char* wsb = (char*)d_ws;
  size_t off = 0;
  auto alloc = [&](size_t bytes) -> void* {
    void* p = wsb + off; off += (bytes + 255) & ~(size_t)255; return p;
  };
  float*           h        = (float*)          alloc((size_t)M_ * E_ * 4);
  __hip_bfloat16*  y_bf     = (__hip_bfloat16*) alloc((size_t)M_ * E_ * 2);
  __hip_bfloat16*  qkv_bf   = (__hip_bfloat16*) alloc((size_t)M_ * QKVW_ * 2);
  __hip_bfloat16*  vt_bf    = (__hip_bfloat16*) alloc((size_t)B_ * H_ * HD_ * N_ * 2);
  __hip_bfloat16*  o_bf     = (__hip_bfloat16*) alloc((size_t)M_ * E_ * 2);
  __hip_bfloat16*  mid_bf   = (__hip_bfloat16*) alloc((size_t)M_ * FF_ * 2);
  __hip_bfloat16*  whead_bt = (__hip_bfloat16*) alloc((size_t)VPAD_ * E_ * 2);
  bool preall = (off + (size_t)6 * WSLAB_ * 2 <= ws_size);
  __hip_bfloat16* wslab = (__hip_bfloat16*) alloc(((size_t)(preall ? 6 : 1)) * WSLAB_ * 2);

  dim3 blk(256);

  embed_kernel<<<(B_ * N_ * E_ + 255) / 256, blk, 0, stream>>>(x, tok, h);
  transpose_cast_kernel<<<dim3(E_ / 64, VPAD_ / 64), blk, 0, stream>>>(whead, whead_bt, E_, V_);
  if (preall)
    wtrans_kernel<<<6 * 1728, blk, 0, stream>>>(wq, wk, wv, wo, w1, w2, wslab, 0);

  dim3 gqkv(QKVW_ / 64, M_ / 128);    // BN=64: 36x16 = 576 blocks
  dim3 gffn1(FF_ / 64, M_ / 128);     // BN=64: 48x16 = 768 blocks
  dim3 g64(E_ / 64, M_ / 128);        // 12x16 = 192 blocks
  dim3 gfa(N_ / 16, H_, B_);

  for (int l = 0; l < L_; ++l) {
    if (!preall)
      wtrans_kernel<<<1728, blk, 0, stream>>>(wq, wk, wv, wo, w1, w2, wslab, l);
    __hip_bfloat16* wb = wslab + (preall ? (size_t)l * WSLAB_ : 0);

    layernorm_kernel<<<M_, blk, 0, stream>>>(h, y_bf, ln1g + (size_t)l * E_, ln1b + (size_t)l * E_);
    gemm_bt_kernel<64><<<gqkv, blk, 0, stream>>>(y_bf, wb + OFF_QKV_, nullptr, nullptr,
        nullptr, qkv_bf, vt_bf, QKVW_, E_, 0, 0);
    fattn_kernel<<<gfa, dim3(64), 0, stream>>>(qkv_bf, vt_bf, o_bf);
    gemm_bt_kernel<64><<<g64, blk, 0, stream>>>(o_bf, wb + OFF_WO_, bo + (size_t)l * E_, h,
        h, nullptr, nullptr, E_, E_, 0, 0);
    layernorm_kernel<<<M_, blk, 0, stream>>>(h, y_bf, ln2g + (size_t)l * E_, ln2b + (size_t)l * E_);
    gemm_bt_kernel<64><<<gffn1, blk, 0, stream>>>(y_bf, wb + OFF_W1_, b1 + (size_t)l * FF_,
        nullptr, nullptr, mid_bf, nullptr, FF_, E_, 1, 0);
    gemm_bt_kernel<64><<<g64, blk, 0, stream>>>(mid_bf, wb + OFF_W2_, b2 + (size_t)l * E_, h,
        h, nullptr, nullptr, E_, FF_, 0, 0);
  }

  layernorm_kernel<<<M_, blk, 0, stream>>>(h, y_bf, lnfg, lnfb);
  gemm_bt_kernel<128><<<dim3((VPAD_ / 128) * (M_ / 128)), blk, 0, stream>>>(
      y_bf, whead_bt, nullptr, nullptr, out, nullptr, nullptr, V_, E_, 2, M_ / 128);
}

// Round 8
// 1430.725 us; speedup vs baseline: 9.5660x; 1.0034x over previous
//
#include <hip/hip_runtime.h>
#include <hip/hip_bf16.h>
#include <math.h>

#define B_  2
#define N_  1024
#define E_  768
#define H_  12
#define HD_ 64
#define L_  6
#define FF_ 3072
#define V_  50257
#define VPAD_ 50304
#define QKVW_ 2304
#define M_  (B_ * N_)   // 2048

// per-layer transposed-weight slab (bf16 element offsets)
#define OFF_QKV_ 0
#define OFF_WO_  (QKVW_ * E_)
#define OFF_W1_  (OFF_WO_ + E_ * E_)
#define OFF_W2_  (OFF_W1_ + FF_ * E_)
#define WSLAB_   ((size_t)(OFF_W2_ + E_ * FF_))   // 7077888 elems

typedef short short8 __attribute__((ext_vector_type(8)));
typedef float f32x4 __attribute__((ext_vector_type(4)));

__device__ __forceinline__ float gelu_f(float x) {
  return 0.5f * x * (1.0f + tanhf(0.7978845608028654f * (x + 0.044715f * x * x * x)));
}

__device__ __forceinline__ unsigned short f2bf(float f) {
  __hip_bfloat16 b = __float2bfloat16(f);
  return *reinterpret_cast<unsigned short*>(&b);
}

__device__ __forceinline__ void async_ld16(const void* g, void* l) {
  __builtin_amdgcn_global_load_lds(
      (const __attribute__((address_space(1))) void*)g,
      (__attribute__((address_space(3))) void*)l, 16, 0, 0);
}

// ---------------- embed ----------------
__global__ __launch_bounds__(256) void embed_kernel(const int* __restrict__ x,
    const float* __restrict__ tok, float* __restrict__ h) {
  int idx = blockIdx.x * 256 + threadIdx.x;
  const int total = B_ * N_ * E_;
  if (idx >= total) return;
  int e  = idx % E_;
  int bn = idx / E_;
  int n  = bn % N_;
  int t  = x[bn];
  float freq = expf(-9.210340371976184f * (float)(2 * e) / (float)E_);
  float arg  = (float)n * freq;
  float pe   = (e & 1) ? cosf(arg) : sinf(arg);
  h[idx] = tok[(size_t)t * E_ + e] + pe;
}

// ---------------- layernorm: fp32 in -> bf16 out ----------------
__global__ __launch_bounds__(256) void layernorm_kernel(const float* __restrict__ in,
    __hip_bfloat16* __restrict__ out, const float* __restrict__ g, const float* __restrict__ b) {
  int row = blockIdx.x;
  const float* xr = in + (size_t)row * E_;
  __shared__ float red[256];
  int tid = threadIdx.x;
  float s = 0.f, ss = 0.f;
  for (int e = tid; e < E_; e += 256) { float v = xr[e]; s += v; ss += v * v; }
  red[tid] = s; __syncthreads();
  for (int o = 128; o > 0; o >>= 1) { if (tid < o) red[tid] += red[tid + o]; __syncthreads(); }
  float mean = red[0] / (float)E_;
  __syncthreads();
  red[tid] = ss; __syncthreads();
  for (int o = 128; o > 0; o >>= 1) { if (tid < o) red[tid] += red[tid + o]; __syncthreads(); }
  float var = red[0] / (float)E_ - mean * mean;
  float inv = rsqrtf(var + 1e-5f);
  for (int e = tid; e < E_; e += 256)
    out[(size_t)row * E_ + e] = __float2bfloat16(g[e] * (xr[e] - mean) * inv + b[e]);
}

// ---------------- transpose + cast (head weight) ----------------
__global__ __launch_bounds__(256) void transpose_cast_kernel(const float* __restrict__ in,
    __hip_bfloat16* __restrict__ out, int K, int Nn) {
  __shared__ float t[64][65];
  int k0 = blockIdx.x * 64, n0 = blockIdx.y * 64;
  int tid = threadIdx.x;
  int c = tid & 63, rg = tid >> 6;
#pragma unroll
  for (int i = 0; i < 16; ++i) {
    int r = rg * 16 + i;
    int n = n0 + c;
    t[r][c] = (n < Nn) ? in[(size_t)(k0 + r) * Nn + n] : 0.0f;
  }
  __syncthreads();
#pragma unroll
  for (int i = 0; i < 16; ++i) {
    int ro = rg * 16 + i;
    out[(size_t)(n0 + ro) * K + (k0 + c)] = __float2bfloat16(t[c][ro]);
  }
}

// ---------------- per-layer weight transposes ----------------
__global__ __launch_bounds__(256) void wtrans_kernel(
    const float* __restrict__ wq, const float* __restrict__ wk,
    const float* __restrict__ wv, const float* __restrict__ wo,
    const float* __restrict__ w1, const float* __restrict__ w2,
    __hip_bfloat16* __restrict__ out, int l0) {
  int bid = blockIdx.x;
  int lay = bid / 1728;
  int t = bid - lay * 1728;
  int lsrc = l0 + lay;
  __hip_bfloat16* ob = out + (size_t)lay * WSLAB_;
  const float* src; __hip_bfloat16* dst;
  int K, Nn, ntk;
  if (t < 576) {
    int which = t / 144; t -= which * 144;
    K = E_; Nn = E_; ntk = 12;
    if (which == 0)      { src = wq + (size_t)lsrc * E_ * E_; dst = ob + OFF_QKV_; }
    else if (which == 1) { src = wk + (size_t)lsrc * E_ * E_; dst = ob + OFF_QKV_ + (size_t)E_ * E_; }
    else if (which == 2) { src = wv + (size_t)lsrc * E_ * E_; dst = ob + OFF_QKV_ + (size_t)2 * E_ * E_; }
    else                 { src = wo + (size_t)lsrc * E_ * E_; dst = ob + OFF_WO_; }
  } else if (t < 1152) {
    t -= 576; K = E_; Nn = FF_; ntk = 12;
    src = w1 + (size_t)lsrc * E_ * FF_; dst = ob + OFF_W1_;
  } else {
    t -= 1152; K = FF_; Nn = E_; ntk = 48;
    src = w2 + (size_t)lsrc * FF_ * E_; dst = ob + OFF_W2_;
  }
  int kt = t % ntk, nt = t / ntk;
  int k0 = kt * 64, n0 = nt * 64;
  __shared__ float tt[64][65];
  int tid = threadIdx.x;
  int c = tid & 63, rg = tid >> 6;
#pragma unroll
  for (int i = 0; i < 16; ++i) {
    int r = rg * 16 + i;
    tt[r][c] = src[(size_t)(k0 + r) * Nn + n0 + c];
  }
  __syncthreads();
#pragma unroll
  for (int i = 0; i < 16; ++i) {
    int ro = rg * 16 + i;
    dst[(size_t)(n0 + ro) * K + (k0 + c)] = __float2bfloat16(tt[c][ro]);
  }
}

// ---------------- MFMA GEMM: C[BM x 64 per block] = A[M,K] @ Bt[Npad,K]^T ----------------
// BK=64 rows (128B), 4 waves as BM/4-row stripes (each wave covers all 64 cols).
// Conflict-free row-XOR swizzle (r6-verified: conflicts=0). 2-phase double-buffer:
// issue STAGE(t+1) -> ds_read+MFMA(t) -> ONE barrier per K-step.
// BM=128: 48KB LDS (3 blocks/CU). BM=64: 32KB (5 blocks/CU) for grid-starved GEMMs.
// flags&1: GELU. flags&2: fp32 LDS-transposed coalesced nt-store epilogue (head).
// nrt>0: 1-D launch, XCD-chunked column-panel-major remap.
template<int BM>
__global__ __launch_bounds__(256) void gemm_bt_kernel(
    const __hip_bfloat16* __restrict__ A, const __hip_bfloat16* __restrict__ Bt,
    const float* __restrict__ bias, const float* __restrict__ R,
    float* __restrict__ Cf, __hip_bfloat16* __restrict__ Cb,
    __hip_bfloat16* __restrict__ vt,
    int Nn, int K, int flags, int nrt) {
  constexpr int NROWS = BM + 64;
  constexpr int WRT = BM / 4;        // wave row-tile
  constexpr int MF  = WRT / 16;      // m-fragments per wave
  __shared__ __align__(16) unsigned short SM[2 * NROWS * 64];  // double-buffered
  int tid = threadIdx.x;
  int w = tid >> 6, l = tid & 63;
  int bx, by;
  if (nrt > 0) {
    int bid = blockIdx.x;
    int q = gridDim.x >> 3;
    int nb = (bid & 7) * q + (bid >> 3);
    bx = nb / nrt; by = nb - bx * nrt;
  } else { bx = blockIdx.x; by = blockIdx.y; }
  int row0 = by * BM, col0 = bx * 64;
  int lr = l & 15, kg = l >> 4;
  const unsigned short* Ag = (const unsigned short*)A;
  const unsigned short* Bg = (const unsigned short*)Bt;
  int srow = l >> 3;                 // 0..7 within 8-row staging group
  int schunk = (l & 7) ^ srow;       // pre-swizzled source 16B-chunk (0..7)

  constexpr int NS = NROWS / 32;     // staging rounds (8 rows per wave-instr, 4 waves)
  constexpr int A8 = BM / 8;         // 8-row groups in A tile
  auto stage = [&](int buf, int k0) {
    unsigned short* As = SM + buf * (NROWS * 64);
    unsigned short* Bs = As + BM * 64;
#pragma unroll
    for (int s = 0; s < NS; ++s) {
      int idx8 = s * 4 + w;          // 8-row block index, wave-uniform
      if (idx8 < A8)
        async_ld16(Ag + (size_t)(row0 + idx8 * 8 + srow) * K + k0 + schunk * 8,
                   &As[idx8 * 8 * 64]);
      else
        async_ld16(Bg + (size_t)(col0 + (idx8 - A8) * 8 + srow) * K + k0 + schunk * 8,
                   &Bs[(idx8 - A8) * 8 * 64]);
    }
  };

  f32x4 acc[MF][4];
#pragma unroll
  for (int m = 0; m < MF; ++m)
#pragma unroll
    for (int n = 0; n < 4; ++n) acc[m][n] = (f32x4){0.f, 0.f, 0.f, 0.f};

  int nt = K >> 6;
  stage(0, 0);
  __syncthreads();                   // buf0 ready
  int cur = 0;
  for (int t = 0; t < nt; ++t) {
    if (t + 1 < nt) stage(cur ^ 1, (t + 1) << 6);   // issue next tile first
    const unsigned short* As = SM + cur * (NROWS * 64);
    const unsigned short* Bs = As + BM * 64;
#pragma unroll
    for (int hf = 0; hf < 2; ++hf) {
      short8 af[MF], bf[4];
#pragma unroll
      for (int m = 0; m < MF; ++m) {
        int r = w * WRT + m * 16 + lr;
        af[m] = *(const short8*)&As[r * 64 + ((((hf << 2) | kg)) ^ (lr & 7)) * 8];
      }
#pragma unroll
      for (int n = 0; n < 4; ++n) {
        int r = n * 16 + lr;
        bf[n] = *(const short8*)&Bs[r * 64 + ((((hf << 2) | kg)) ^ (lr & 7)) * 8];
      }
#pragma unroll
      for (int m = 0; m < MF; ++m)
#pragma unroll
        for (int n = 0; n < 4; ++n)
          acc[m][n] = __builtin_amdgcn_mfma_f32_16x16x32_bf16(af[m], bf[n], acc[m][n], 0, 0, 0);
    }
    if (t + 1 < nt) { __syncthreads(); cur ^= 1; }  // drain next tile; protect old buf
  }

  if (flags & 2) {
    // fp32 epilogue: LDS-transpose (2-way-free banking) + coalesced nt stores
    float* Ls = (float*)SM;          // BM x 64 fp32 = BM/2 KB (fits: SM >= 32KB)
    __syncthreads();
#pragma unroll
    for (int m = 0; m < MF; ++m)
#pragma unroll
      for (int n = 0; n < 4; ++n)
#pragma unroll
        for (int j = 0; j < 4; ++j) {
          int r = w * WRT + m * 16 + kg * 4 + j;
          int c = n * 16 + lr;
          Ls[r * 64 + (c ^ (16 * (kg & 1)))] = acc[m][n][j];
        }
    __syncthreads();
    bool nfull = (col0 + 64 <= Nn);
    constexpr int ITER = BM * 64 / 256;
#pragma unroll
    for (int i = 0; i < ITER; ++i) {
      int idx = i * 256 + tid;
      int r = idx >> 6, c = idx & 63;
      float v = Ls[r * 64 + (c ^ (16 * ((r >> 2) & 1)))];
      if (nfull || col0 + c < Nn)
        __builtin_nontemporal_store(v, &Cf[(size_t)(row0 + r) * Nn + col0 + c]);
    }
    return;
  }

  unsigned short* vtb = (unsigned short*)vt;
#pragma unroll
  for (int n = 0; n < 4; ++n) {
    int col = col0 + n * 16 + lr;
    if (col >= Nn) continue;
    float bv = bias ? bias[col] : 0.f;
    bool to_vt = (vtb != nullptr) && (col >= 2 * E_);
    int hh = 0, dd = 0;
    if (to_vt) { int c2 = col - 2 * E_; hh = c2 >> 6; dd = c2 & 63; }
#pragma unroll
    for (int m = 0; m < MF; ++m) {
#pragma unroll
      for (int j = 0; j < 4; ++j) {
        int row = row0 + w * WRT + m * 16 + kg * 4 + j;
        float val = acc[m][n][j] + bv;
        if (flags & 1) val = gelu_f(val);
        if (R) val += R[(size_t)row * Nn + col];
        if (Cf) Cf[(size_t)row * Nn + col] = val;
        if (to_vt) {
          int bz = row >> 10, nn = row & (N_ - 1);
          vtb[((size_t)(bz * H_ + hh) * HD_ + dd) * N_ + nn] = f2bf(val);
        } else if (Cb) {
          Cb[(size_t)row * Nn + col] = __float2bfloat16(val);
        }
      }
    }
  }
}

// ---------------- flash attention: 1 wave/block, 16 q-rows, 32-key steps ----------------
#define PRS_ 40
__global__ __launch_bounds__(64) void fattn_kernel(
    const __hip_bfloat16* __restrict__ qkv, const __hip_bfloat16* __restrict__ vt,
    __hip_bfloat16* __restrict__ o) {
  int qt = blockIdx.x, hh = blockIdx.y, bz = blockIdx.z;
  int q0 = qt * 16;
  int l = threadIdx.x;
  int lr = l & 15, kg = l >> 4;
  const unsigned short* base = (const unsigned short*)qkv;
  const unsigned short* vtb = (const unsigned short*)vt + ((size_t)(bz * H_ + hh)) * HD_ * N_;
  __shared__ __align__(16) unsigned short P[16 * PRS_];

  short8 qf[2];
  const unsigned short* qrow = base + (size_t)(bz * N_ + q0 + lr) * QKVW_ + hh * HD_;
#pragma unroll
  for (int c = 0; c < 2; ++c) qf[c] = *(const short8*)(qrow + c * 32 + kg * 8);

  float mrow[4], lsum[4];
  f32x4 accO[4];
#pragma unroll
  for (int j = 0; j < 4; ++j) { mrow[j] = -INFINITY; lsum[j] = 0.f; }
#pragma unroll
  for (int db = 0; db < 4; ++db) accO[db] = (f32x4){0.f, 0.f, 0.f, 0.f};

  int nsteps = (q0 + 16 + 31) / 32;
  for (int kt = 0; kt < nsteps; ++kt) {
    f32x4 s[2];
#pragma unroll
    for (int t = 0; t < 2; ++t) {
      const unsigned short* krow = base + (size_t)(bz * N_ + kt * 32 + t * 16 + lr) * QKVW_ + E_ + hh * HD_;
      short8 kf0 = *(const short8*)(krow + kg * 8);
      short8 kf1 = *(const short8*)(krow + 32 + kg * 8);
      f32x4 acc = (f32x4){0.f, 0.f, 0.f, 0.f};
      acc = __builtin_amdgcn_mfma_f32_16x16x32_bf16(qf[0], kf0, acc, 0, 0, 0);
      acc = __builtin_amdgcn_mfma_f32_16x16x32_bf16(qf[1], kf1, acc, 0, 0, 0);
      s[t] = acc;
    }
    float pm[2][4];
#pragma unroll
    for (int t = 0; t < 2; ++t) {
      int kglob = kt * 32 + t * 16 + lr;
#pragma unroll
      for (int j = 0; j < 4; ++j) {
        int qglob = q0 + kg * 4 + j;
        pm[t][j] = (kglob <= qglob) ? s[t][j] * 0.125f : -INFINITY;
      }
    }
#pragma unroll
    for (int j = 0; j < 4; ++j) {
      float tm = fmaxf(pm[0][j], pm[1][j]);
      tm = fmaxf(tm, __shfl_xor(tm, 1));
      tm = fmaxf(tm, __shfl_xor(tm, 2));
      tm = fmaxf(tm, __shfl_xor(tm, 4));
      tm = fmaxf(tm, __shfl_xor(tm, 8));
      float mnew = fmaxf(mrow[j], tm);
      float alpha = __expf(mrow[j] - mnew);
      float p0 = __expf(pm[0][j] - mnew);
      float p1 = __expf(pm[1][j] - mnew);
      float rs = p0 + p1;
      rs += __shfl_xor(rs, 1);
      rs += __shfl_xor(rs, 2);
      rs += __shfl_xor(rs, 4);
      rs += __shfl_xor(rs, 8);
      lsum[j] = lsum[j] * alpha + rs;
      mrow[j] = mnew;
#pragma unroll
      for (int db = 0; db < 4; ++db) accO[db][j] *= alpha;
      P[(kg * 4 + j) * PRS_ + lr]      = f2bf(p0);
      P[(kg * 4 + j) * PRS_ + 16 + lr] = f2bf(p1);
    }
    __syncthreads();
    short8 pa = *(const short8*)&P[lr * PRS_ + kg * 8];
#pragma unroll
    for (int db = 0; db < 4; ++db) {
      short8 vf = *(const short8*)(vtb + (size_t)(db * 16 + lr) * N_ + kt * 32 + kg * 8);
      accO[db] = __builtin_amdgcn_mfma_f32_16x16x32_bf16(pa, vf, accO[db], 0, 0, 0);
    }
    __syncthreads();
  }
  unsigned short* ob = (unsigned short*)o;
#pragma unroll
  for (int j = 0; j < 4; ++j) {
    float inv = 1.f / lsum[j];
    size_t orow = (size_t)(bz * N_ + q0 + kg * 4 + j) * E_ + hh * HD_;
#pragma unroll
    for (int db = 0; db < 4; ++db)
      ob[orow + db * 16 + lr] = f2bf(accO[db][j] * inv);
  }
}

extern "C" void kernel_launch(void* const* d_in, const int* in_sizes, int n_in,
                              void* d_out, int out_size, void* d_ws, size_t ws_size,
                              hipStream_t stream) {
  const int*   x     = (const int*)  d_in[0];
  const float* tok   = (const float*)d_in[1];
  const float* wq    = (const float*)d_in[2];
  const float* wk    = (const float*)d_in[3];
  const float* wv    = (const float*)d_in[4];
  const float* wo    = (const float*)d_in[5];
  const float* bo    = (const float*)d_in[6];
  const float* ln1g  = (const float*)d_in[7];
  const float* ln1b  = (const float*)d_in[8];
  const float* ln2g  = (const float*)d_in[9];
  const float* ln2b  = (const float*)d_in[10];
  const float* w1    = (const float*)d_in[11];
  const float* b1    = (const float*)d_in[12];
  const float* w2    = (const float*)d_in[13];
  const float* b2    = (const float*)d_in[14];
  const float* lnfg  = (const float*)d_in[15];
  const float* lnfb  = (const float*)d_in[16];
  const float* whead = (const float*)d_in[17];
  float* out = (float*)d_out;

  char* wsb = (char*)d_ws;
  size_t off = 0;
  auto alloc = [&](size_t bytes) -> void* {
    void* p = wsb + off; off += (bytes + 255) & ~(size_t)255; return p;
  };
  float*           h        = (float*)          alloc((size_t)M_ * E_ * 4);
  __hip_bfloat16*  y_bf     = (__hip_bfloat16*) alloc((size_t)M_ * E_ * 2);
  __hip_bfloat16*  qkv_bf   = (__hip_bfloat16*) alloc((size_t)M_ * QKVW_ * 2);
  __hip_bfloat16*  vt_bf    = (__hip_bfloat16*) alloc((size_t)B_ * H_ * HD_ * N_ * 2);
  __hip_bfloat16*  o_bf     = (__hip_bfloat16*) alloc((size_t)M_ * E_ * 2);
  __hip_bfloat16*  mid_bf   = (__hip_bfloat16*) alloc((size_t)M_ * FF_ * 2);
  __hip_bfloat16*  whead_bt = (__hip_bfloat16*) alloc((size_t)VPAD_ * E_ * 2);
  bool preall = (off + (size_t)6 * WSLAB_ * 2 <= ws_size);
  __hip_bfloat16* wslab = (__hip_bfloat16*) alloc(((size_t)(preall ? 6 : 1)) * WSLAB_ * 2);

  dim3 blk(256);

  embed_kernel<<<(B_ * N_ * E_ + 255) / 256, blk, 0, stream>>>(x, tok, h);
  transpose_cast_kernel<<<dim3(E_ / 64, VPAD_ / 64), blk, 0, stream>>>(whead, whead_bt, E_, V_);
  if (preall)
    wtrans_kernel<<<6 * 1728, blk, 0, stream>>>(wq, wk, wv, wo, w1, w2, wslab, 0);

  dim3 gqkv(QKVW_ / 64, M_ / 128);    // 36x16 = 576 blocks
  dim3 gffn1(FF_ / 64, M_ / 128);     // 48x16 = 768 blocks
  dim3 gsm(E_ / 64, M_ / 64);         // BM=64: 12x32 = 384 blocks (wo, ffn2)
  dim3 gfa(N_ / 16, H_, B_);

  for (int l = 0; l < L_; ++l) {
    if (!preall)
      wtrans_kernel<<<1728, blk, 0, stream>>>(wq, wk, wv, wo, w1, w2, wslab, l);
    __hip_bfloat16* wb = wslab + (preall ? (size_t)l * WSLAB_ : 0);

    layernorm_kernel<<<M_, blk, 0, stream>>>(h, y_bf, ln1g + (size_t)l * E_, ln1b + (size_t)l * E_);
    gemm_bt_kernel<128><<<gqkv, blk, 0, stream>>>(y_bf, wb + OFF_QKV_, nullptr, nullptr,
        nullptr, qkv_bf, vt_bf, QKVW_, E_, 0, 0);
    fattn_kernel<<<gfa, dim3(64), 0, stream>>>(qkv_bf, vt_bf, o_bf);
    gemm_bt_kernel<64><<<gsm, blk, 0, stream>>>(o_bf, wb + OFF_WO_, bo + (size_t)l * E_, h,
        h, nullptr, nullptr, E_, E_, 0, 0);
    layernorm_kernel<<<M_, blk, 0, stream>>>(h, y_bf, ln2g + (size_t)l * E_, ln2b + (size_t)l * E_);
    gemm_bt_kernel<128><<<gffn1, blk, 0, stream>>>(y_bf, wb + OFF_W1_, b1 + (size_t)l * FF_,
        nullptr, nullptr, mid_bf, nullptr, FF_, E_, 1, 0);
    gemm_bt_kernel<64><<<gsm, blk, 0, stream>>>(mid_bf, wb + OFF_W2_, b2 + (size_t)l * E_, h,
        h, nullptr, nullptr, E_, FF_, 0, 0);
  }

  layernorm_kernel<<<M_, blk, 0, stream>>>(h, y_bf, lnfg, lnfb);
  // head: BM=128 x 64-col tiles, 1-D XCD-panel remap, fp32 coalesced nt epilogue
  gemm_bt_kernel<128><<<dim3((VPAD_ / 64) * (M_ / 128)), blk, 0, stream>>>(
      y_bf, whead_bt, nullptr, nullptr, out, nullptr, nullptr, V_, E_, 2, M_ / 128);
}

// Round 9
// 1337.017 us; speedup vs baseline: 10.2364x; 1.0701x over previous
//
#include <hip/hip_runtime.h>
#include <hip/hip_bf16.h>
#include <math.h>

#define B_  2
#define N_  1024
#define E_  768
#define H_  12
#define HD_ 64
#define L_  6
#define FF_ 3072
#define V_  50257
#define VPAD_ 50304
#define QKVW_ 2304
#define M_  (B_ * N_)   // 2048

// per-layer transposed-weight slab (bf16 element offsets)
#define OFF_QKV_ 0
#define OFF_WO_  (QKVW_ * E_)
#define OFF_W1_  (OFF_WO_ + E_ * E_)
#define OFF_W2_  (OFF_W1_ + FF_ * E_)
#define WSLAB_   ((size_t)(OFF_W2_ + E_ * FF_))   // 7077888 elems

typedef short short8 __attribute__((ext_vector_type(8)));
typedef float f32x4 __attribute__((ext_vector_type(4)));

__device__ __forceinline__ float gelu_f(float x) {
  return 0.5f * x * (1.0f + tanhf(0.7978845608028654f * (x + 0.044715f * x * x * x)));
}

__device__ __forceinline__ unsigned short f2bf(float f) {
  __hip_bfloat16 b = __float2bfloat16(f);
  return *reinterpret_cast<unsigned short*>(&b);
}

__device__ __forceinline__ void async_ld16(const void* g, void* l) {
  __builtin_amdgcn_global_load_lds(
      (const __attribute__((address_space(1))) void*)g,
      (__attribute__((address_space(3))) void*)l, 16, 0, 0);
}

// ---------------- embed ----------------
__global__ __launch_bounds__(256) void embed_kernel(const int* __restrict__ x,
    const float* __restrict__ tok, float* __restrict__ h) {
  int idx = blockIdx.x * 256 + threadIdx.x;
  const int total = B_ * N_ * E_;
  if (idx >= total) return;
  int e  = idx % E_;
  int bn = idx / E_;
  int n  = bn % N_;
  int t  = x[bn];
  float freq = expf(-9.210340371976184f * (float)(2 * e) / (float)E_);
  float arg  = (float)n * freq;
  float pe   = (e & 1) ? cosf(arg) : sinf(arg);
  h[idx] = tok[(size_t)t * E_ + e] + pe;
}

// ---------------- layernorm: fp32 in -> bf16 out ----------------
__global__ __launch_bounds__(256) void layernorm_kernel(const float* __restrict__ in,
    __hip_bfloat16* __restrict__ out, const float* __restrict__ g, const float* __restrict__ b) {
  int row = blockIdx.x;
  const float* xr = in + (size_t)row * E_;
  __shared__ float red[256];
  int tid = threadIdx.x;
  float s = 0.f, ss = 0.f;
  for (int e = tid; e < E_; e += 256) { float v = xr[e]; s += v; ss += v * v; }
  red[tid] = s; __syncthreads();
  for (int o = 128; o > 0; o >>= 1) { if (tid < o) red[tid] += red[tid + o]; __syncthreads(); }
  float mean = red[0] / (float)E_;
  __syncthreads();
  red[tid] = ss; __syncthreads();
  for (int o = 128; o > 0; o >>= 1) { if (tid < o) red[tid] += red[tid + o]; __syncthreads(); }
  float var = red[0] / (float)E_ - mean * mean;
  float inv = rsqrtf(var + 1e-5f);
  for (int e = tid; e < E_; e += 256)
    out[(size_t)row * E_ + e] = __float2bfloat16(g[e] * (xr[e] - mean) * inv + b[e]);
}

// ---------------- transpose + cast (head weight) ----------------
__global__ __launch_bounds__(256) void transpose_cast_kernel(const float* __restrict__ in,
    __hip_bfloat16* __restrict__ out, int K, int Nn) {
  __shared__ float t[64][65];
  int k0 = blockIdx.x * 64, n0 = blockIdx.y * 64;
  int tid = threadIdx.x;
  int c = tid & 63, rg = tid >> 6;
#pragma unroll
  for (int i = 0; i < 16; ++i) {
    int r = rg * 16 + i;
    int n = n0 + c;
    t[r][c] = (n < Nn) ? in[(size_t)(k0 + r) * Nn + n] : 0.0f;
  }
  __syncthreads();
#pragma unroll
  for (int i = 0; i < 16; ++i) {
    int ro = rg * 16 + i;
    out[(size_t)(n0 + ro) * K + (k0 + c)] = __float2bfloat16(t[c][ro]);
  }
}

// ---------------- per-layer weight transposes ----------------
__global__ __launch_bounds__(256) void wtrans_kernel(
    const float* __restrict__ wq, const float* __restrict__ wk,
    const float* __restrict__ wv, const float* __restrict__ wo,
    const float* __restrict__ w1, const float* __restrict__ w2,
    __hip_bfloat16* __restrict__ out, int l0) {
  int bid = blockIdx.x;
  int lay = bid / 1728;
  int t = bid - lay * 1728;
  int lsrc = l0 + lay;
  __hip_bfloat16* ob = out + (size_t)lay * WSLAB_;
  const float* src; __hip_bfloat16* dst;
  int K, Nn, ntk;
  if (t < 576) {
    int which = t / 144; t -= which * 144;
    K = E_; Nn = E_; ntk = 12;
    if (which == 0)      { src = wq + (size_t)lsrc * E_ * E_; dst = ob + OFF_QKV_; }
    else if (which == 1) { src = wk + (size_t)lsrc * E_ * E_; dst = ob + OFF_QKV_ + (size_t)E_ * E_; }
    else if (which == 2) { src = wv + (size_t)lsrc * E_ * E_; dst = ob + OFF_QKV_ + (size_t)2 * E_ * E_; }
    else                 { src = wo + (size_t)lsrc * E_ * E_; dst = ob + OFF_WO_; }
  } else if (t < 1152) {
    t -= 576; K = E_; Nn = FF_; ntk = 12;
    src = w1 + (size_t)lsrc * E_ * FF_; dst = ob + OFF_W1_;
  } else {
    t -= 1152; K = FF_; Nn = E_; ntk = 48;
    src = w2 + (size_t)lsrc * FF_ * E_; dst = ob + OFF_W2_;
  }
  int kt = t % ntk, nt = t / ntk;
  int k0 = kt * 64, n0 = nt * 64;
  __shared__ float tt[64][65];
  int tid = threadIdx.x;
  int c = tid & 63, rg = tid >> 6;
#pragma unroll
  for (int i = 0; i < 16; ++i) {
    int r = rg * 16 + i;
    tt[r][c] = src[(size_t)(k0 + r) * Nn + n0 + c];
  }
  __syncthreads();
#pragma unroll
  for (int i = 0; i < 16; ++i) {
    int ro = rg * 16 + i;
    dst[(size_t)(n0 + ro) * K + (k0 + c)] = __float2bfloat16(tt[c][ro]);
  }
}

// ---------------- layer MFMA GEMM: C[BM x 64 per block] = A @ Bt^T ----------------
// (unchanged from r8: BK=64 rows, 4 waves as BM/4-row stripes, conflict-free
//  row-XOR swizzle, 2-phase double-buffer, one barrier per K-step)
template<int BM>
__global__ __launch_bounds__(256) void gemm_bt_kernel(
    const __hip_bfloat16* __restrict__ A, const __hip_bfloat16* __restrict__ Bt,
    const float* __restrict__ bias, const float* __restrict__ R,
    float* __restrict__ Cf, __hip_bfloat16* __restrict__ Cb,
    __hip_bfloat16* __restrict__ vt,
    int Nn, int K, int flags) {
  constexpr int NROWS = BM + 64;
  constexpr int WRT = BM / 4;        // wave row-tile
  constexpr int MF  = WRT / 16;      // m-fragments per wave
  __shared__ __align__(16) unsigned short SM[2 * NROWS * 64];  // double-buffered
  int tid = threadIdx.x;
  int w = tid >> 6, l = tid & 63;
  int bx = blockIdx.x, by = blockIdx.y;
  int row0 = by * BM, col0 = bx * 64;
  int lr = l & 15, kg = l >> 4;
  const unsigned short* Ag = (const unsigned short*)A;
  const unsigned short* Bg = (const unsigned short*)Bt;
  int srow = l >> 3;                 // 0..7 within 8-row staging group
  int schunk = (l & 7) ^ srow;       // pre-swizzled source 16B-chunk (0..7)

  constexpr int NS = NROWS / 32;     // staging rounds (8 rows per wave-instr, 4 waves)
  constexpr int A8 = BM / 8;         // 8-row groups in A tile
  auto stage = [&](int buf, int k0) {
    unsigned short* As = SM + buf * (NROWS * 64);
    unsigned short* Bs = As + BM * 64;
#pragma unroll
    for (int s = 0; s < NS; ++s) {
      int idx8 = s * 4 + w;          // 8-row block index, wave-uniform
      if (idx8 < A8)
        async_ld16(Ag + (size_t)(row0 + idx8 * 8 + srow) * K + k0 + schunk * 8,
                   &As[idx8 * 8 * 64]);
      else
        async_ld16(Bg + (size_t)(col0 + (idx8 - A8) * 8 + srow) * K + k0 + schunk * 8,
                   &Bs[(idx8 - A8) * 8 * 64]);
    }
  };

  f32x4 acc[MF][4];
#pragma unroll
  for (int m = 0; m < MF; ++m)
#pragma unroll
    for (int n = 0; n < 4; ++n) acc[m][n] = (f32x4){0.f, 0.f, 0.f, 0.f};

  int nt = K >> 6;
  stage(0, 0);
  __syncthreads();                   // buf0 ready
  int cur = 0;
  for (int t = 0; t < nt; ++t) {
    if (t + 1 < nt) stage(cur ^ 1, (t + 1) << 6);   // issue next tile first
    const unsigned short* As = SM + cur * (NROWS * 64);
    const unsigned short* Bs = As + BM * 64;
#pragma unroll
    for (int hf = 0; hf < 2; ++hf) {
      short8 af[MF], bf[4];
#pragma unroll
      for (int m = 0; m < MF; ++m) {
        int r = w * WRT + m * 16 + lr;
        af[m] = *(const short8*)&As[r * 64 + ((((hf << 2) | kg)) ^ (lr & 7)) * 8];
      }
#pragma unroll
      for (int n = 0; n < 4; ++n) {
        int r = n * 16 + lr;
        bf[n] = *(const short8*)&Bs[r * 64 + ((((hf << 2) | kg)) ^ (lr & 7)) * 8];
      }
#pragma unroll
      for (int m = 0; m < MF; ++m)
#pragma unroll
        for (int n = 0; n < 4; ++n)
          acc[m][n] = __builtin_amdgcn_mfma_f32_16x16x32_bf16(af[m], bf[n], acc[m][n], 0, 0, 0);
    }
    if (t + 1 < nt) { __syncthreads(); cur ^= 1; }  // drain next tile; protect old buf
  }

  unsigned short* vtb = (unsigned short*)vt;
#pragma unroll
  for (int n = 0; n < 4; ++n) {
    int col = col0 + n * 16 + lr;
    if (col >= Nn) continue;
    float bv = bias ? bias[col] : 0.f;
    bool to_vt = (vtb != nullptr) && (col >= 2 * E_);
    int hh = 0, dd = 0;
    if (to_vt) { int c2 = col - 2 * E_; hh = c2 >> 6; dd = c2 & 63; }
#pragma unroll
    for (int m = 0; m < MF; ++m) {
#pragma unroll
      for (int j = 0; j < 4; ++j) {
        int row = row0 + w * WRT + m * 16 + kg * 4 + j;
        float val = acc[m][n][j] + bv;
        if (flags & 1) val = gelu_f(val);
        if (R) val += R[(size_t)row * Nn + col];
        if (Cf) Cf[(size_t)row * Nn + col] = val;
        if (to_vt) {
          int bz = row >> 10, nn = row & (N_ - 1);
          vtb[((size_t)(bz * H_ + hh) * HD_ + dd) * N_ + nn] = f2bf(val);
        } else if (Cb) {
          Cb[(size_t)row * Nn + col] = __float2bfloat16(val);
        }
      }
    }
  }
}

// ---------------- head GEMM: 128x128 tile, BK=32, 2-phase dbuf in 32KB LDS ----------------
// Combines r6's occupancy (32KB LDS) with r7's pipelining. Rows are 64B (32 shorts):
// source chunk (l&3)^(l>>4), read chunk kg^((lr>>2)&3) -> exactly 2 lanes per 16B slot
// per 16-lane group = 2-way = free (m136). XCD column-panel remap + fp32 LDS-transposed
// coalesced nontemporal epilogue (both r5/r7-verified).
__global__ __launch_bounds__(256) void head_gemm_kernel(
    const __hip_bfloat16* __restrict__ A, const __hip_bfloat16* __restrict__ Bt,
    float* __restrict__ Cf, int Nn, int K, int nrt) {
  __shared__ __align__(16) unsigned short SM[2 * 256 * 32];   // 32 KB
  int tid = threadIdx.x;
  int w = tid >> 6, l = tid & 63;
  int wr = w >> 1, wc = w & 1;
  int bid = blockIdx.x;
  int q = gridDim.x >> 3;           // gridDim.x % 8 == 0
  int nb = (bid & 7) * q + (bid >> 3);
  int bx = nb / nrt, by = nb - bx * nrt;
  int row0 = by * 128, col0 = bx * 128;
  int lr = l & 15, kg = l >> 4;
  const unsigned short* Ag = (const unsigned short*)A;
  const unsigned short* Bg = (const unsigned short*)Bt;
  int srow = l >> 2;                 // row 0..15 within 16-row staging group
  int schunk = (l & 3) ^ (l >> 4);   // pre-swizzled global 16B chunk (0..3)

  auto stage = [&](int buf, int k0) {
    unsigned short* As = SM + buf * (256 * 32);
    unsigned short* Bs = As + 128 * 32;
#pragma unroll
    for (int s = 0; s < 4; ++s) {
      int g = s * 4 + w;             // 16-row group 0..15, wave-uniform
      if (g < 8)
        async_ld16(Ag + (size_t)(row0 + g * 16 + srow) * K + k0 + schunk * 8,
                   &As[g * 16 * 32]);
      else
        async_ld16(Bg + (size_t)(col0 + (g - 8) * 16 + srow) * K + k0 + schunk * 8,
                   &Bs[(g - 8) * 16 * 32]);
    }
  };

  f32x4 acc[4][4];
#pragma unroll
  for (int m = 0; m < 4; ++m)
#pragma unroll
    for (int n = 0; n < 4; ++n) acc[m][n] = (f32x4){0.f, 0.f, 0.f, 0.f};

  int rchunk = (kg ^ ((lr >> 2) & 3)) * 8;
  int nt = K >> 5;                   // 24 steps at K=768
  stage(0, 0);
  __syncthreads();                   // buf0 ready
  int cur = 0;
  for (int t = 0; t < nt; ++t) {
    if (t + 1 < nt) stage(cur ^ 1, (t + 1) << 5);   // issue next tile first
    const unsigned short* As = SM + cur * (256 * 32);
    const unsigned short* Bs = As + 128 * 32;
    short8 af[4], bf[4];
#pragma unroll
    for (int m = 0; m < 4; ++m)
      af[m] = *(const short8*)&As[(wr * 64 + m * 16 + lr) * 32 + rchunk];
#pragma unroll
    for (int n = 0; n < 4; ++n)
      bf[n] = *(const short8*)&Bs[(wc * 64 + n * 16 + lr) * 32 + rchunk];
#pragma unroll
    for (int m = 0; m < 4; ++m)
#pragma unroll
      for (int n = 0; n < 4; ++n)
        acc[m][n] = __builtin_amdgcn_mfma_f32_16x16x32_bf16(af[m], bf[n], acc[m][n], 0, 0, 0);
    if (t + 1 < nt) { __syncthreads(); cur ^= 1; }  // drain next tile; protect old buf
  }

  // fp32 epilogue: LDS-transpose 32 rows/pass (2-way-free banking), coalesced nt stores
  float* Ls = (float*)SM;            // 32 x 128 fp32 = 16 KB
  bool nfull = (col0 + 128 <= Nn);
#pragma unroll
  for (int p = 0; p < 4; ++p) {
    __syncthreads();
    if (wr == (p >> 1)) {
      int mb = (p & 1) * 2;
#pragma unroll
      for (int m2 = 0; m2 < 2; ++m2)
#pragma unroll
        for (int n = 0; n < 4; ++n)
#pragma unroll
          for (int j = 0; j < 4; ++j)
            Ls[(m2 * 16 + kg * 4 + j) * 128 + ((wc * 64 + n * 16 + lr) ^ (16 * (kg & 1)))]
                = acc[mb + m2][n][j];
    }
    __syncthreads();
    int rbase = row0 + p * 32;
    if (nfull) {
#pragma unroll
      for (int i = 0; i < 16; ++i) {
        int idx = i * 256 + tid;
        int r = idx >> 7, c = idx & 127;
        float v = Ls[r * 128 + (c ^ (16 * ((r >> 2) & 1)))];
        __builtin_nontemporal_store(v, &Cf[(size_t)(rbase + r) * Nn + col0 + c]);
      }
    } else {
      for (int i = 0; i < 16; ++i) {
        int idx = i * 256 + tid;
        int r = idx >> 7, c = idx & 127;
        if (col0 + c < Nn) {
          float v = Ls[r * 128 + (c ^ (16 * ((r >> 2) & 1)))];
          __builtin_nontemporal_store(v, &Cf[(size_t)(rbase + r) * Nn + col0 + c]);
        }
      }
    }
  }
}

// ---------------- flash attention: 1 wave/block, 16 q-rows, 32-key steps ----------------
#define PRS_ 40
__global__ __launch_bounds__(64) void fattn_kernel(
    const __hip_bfloat16* __restrict__ qkv, const __hip_bfloat16* __restrict__ vt,
    __hip_bfloat16* __restrict__ o) {
  int qt = blockIdx.x, hh = blockIdx.y, bz = blockIdx.z;
  int q0 = qt * 16;
  int l = threadIdx.x;
  int lr = l & 15, kg = l >> 4;
  const unsigned short* base = (const unsigned short*)qkv;
  const unsigned short* vtb = (const unsigned short*)vt + ((size_t)(bz * H_ + hh)) * HD_ * N_;
  __shared__ __align__(16) unsigned short P[16 * PRS_];

  short8 qf[2];
  const unsigned short* qrow = base + (size_t)(bz * N_ + q0 + lr) * QKVW_ + hh * HD_;
#pragma unroll
  for (int c = 0; c < 2; ++c) qf[c] = *(const short8*)(qrow + c * 32 + kg * 8);

  float mrow[4], lsum[4];
  f32x4 accO[4];
#pragma unroll
  for (int j = 0; j < 4; ++j) { mrow[j] = -INFINITY; lsum[j] = 0.f; }
#pragma unroll
  for (int db = 0; db < 4; ++db) accO[db] = (f32x4){0.f, 0.f, 0.f, 0.f};

  int nsteps = (q0 + 16 + 31) / 32;
  for (int kt = 0; kt < nsteps; ++kt) {
    f32x4 s[2];
#pragma unroll
    for (int t = 0; t < 2; ++t) {
      const unsigned short* krow = base + (size_t)(bz * N_ + kt * 32 + t * 16 + lr) * QKVW_ + E_ + hh * HD_;
      short8 kf0 = *(const short8*)(krow + kg * 8);
      short8 kf1 = *(const short8*)(krow + 32 + kg * 8);
      f32x4 acc = (f32x4){0.f, 0.f, 0.f, 0.f};
      acc = __builtin_amdgcn_mfma_f32_16x16x32_bf16(qf[0], kf0, acc, 0, 0, 0);
      acc = __builtin_amdgcn_mfma_f32_16x16x32_bf16(qf[1], kf1, acc, 0, 0, 0);
      s[t] = acc;
    }
    float pm[2][4];
#pragma unroll
    for (int t = 0; t < 2; ++t) {
      int kglob = kt * 32 + t * 16 + lr;
#pragma unroll
      for (int j = 0; j < 4; ++j) {
        int qglob = q0 + kg * 4 + j;
        pm[t][j] = (kglob <= qglob) ? s[t][j] * 0.125f : -INFINITY;
      }
    }
#pragma unroll
    for (int j = 0; j < 4; ++j) {
      float tm = fmaxf(pm[0][j], pm[1][j]);
      tm = fmaxf(tm, __shfl_xor(tm, 1));
      tm = fmaxf(tm, __shfl_xor(tm, 2));
      tm = fmaxf(tm, __shfl_xor(tm, 4));
      tm = fmaxf(tm, __shfl_xor(tm, 8));
      float mnew = fmaxf(mrow[j], tm);
      float alpha = __expf(mrow[j] - mnew);
      float p0 = __expf(pm[0][j] - mnew);
      float p1 = __expf(pm[1][j] - mnew);
      float rs = p0 + p1;
      rs += __shfl_xor(rs, 1);
      rs += __shfl_xor(rs, 2);
      rs += __shfl_xor(rs, 4);
      rs += __shfl_xor(rs, 8);
      lsum[j] = lsum[j] * alpha + rs;
      mrow[j] = mnew;
#pragma unroll
      for (int db = 0; db < 4; ++db) accO[db][j] *= alpha;
      P[(kg * 4 + j) * PRS_ + lr]      = f2bf(p0);
      P[(kg * 4 + j) * PRS_ + 16 + lr] = f2bf(p1);
    }
    __syncthreads();
    short8 pa = *(const short8*)&P[lr * PRS_ + kg * 8];
#pragma unroll
    for (int db = 0; db < 4; ++db) {
      short8 vf = *(const short8*)(vtb + (size_t)(db * 16 + lr) * N_ + kt * 32 + kg * 8);
      accO[db] = __builtin_amdgcn_mfma_f32_16x16x32_bf16(pa, vf, accO[db], 0, 0, 0);
    }
    __syncthreads();
  }
  unsigned short* ob = (unsigned short*)o;
#pragma unroll
  for (int j = 0; j < 4; ++j) {
    float inv = 1.f / lsum[j];
    size_t orow = (size_t)(bz * N_ + q0 + kg * 4 + j) * E_ + hh * HD_;
#pragma unroll
    for (int db = 0; db < 4; ++db)
      ob[orow + db * 16 + lr] = f2bf(accO[db][j] * inv);
  }
}

extern "C" void kernel_launch(void* const* d_in, const int* in_sizes, int n_in,
                              void* d_out, int out_size, void* d_ws, size_t ws_size,
                              hipStream_t stream) {
  const int*   x     = (const int*)  d_in[0];
  const float* tok   = (const float*)d_in[1];
  const float* wq    = (const float*)d_in[2];
  const float* wk    = (const float*)d_in[3];
  const float* wv    = (const float*)d_in[4];
  const float* wo    = (const float*)d_in[5];
  const float* bo    = (const float*)d_in[6];
  const float* ln1g  = (const float*)d_in[7];
  const float* ln1b  = (const float*)d_in[8];
  const float* ln2g  = (const float*)d_in[9];
  const float* ln2b  = (const float*)d_in[10];
  const float* w1    = (const float*)d_in[11];
  const float* b1    = (const float*)d_in[12];
  const float* w2    = (const float*)d_in[13];
  const float* b2    = (const float*)d_in[14];
  const float* lnfg  = (const float*)d_in[15];
  const float* lnfb  = (const float*)d_in[16];
  const float* whead = (const float*)d_in[17];
  float* out = (float*)d_out;

  char* wsb = (char*)d_ws;
  size_t off = 0;
  auto alloc = [&](size_t bytes) -> void* {
    void* p = wsb + off; off += (bytes + 255) & ~(size_t)255; return p;
  };
  float*           h        = (float*)          alloc((size_t)M_ * E_ * 4);
  __hip_bfloat16*  y_bf     = (__hip_bfloat16*) alloc((size_t)M_ * E_ * 2);
  __hip_bfloat16*  qkv_bf   = (__hip_bfloat16*) alloc((size_t)M_ * QKVW_ * 2);
  __hip_bfloat16*  vt_bf    = (__hip_bfloat16*) alloc((size_t)B_ * H_ * HD_ * N_ * 2);
  __hip_bfloat16*  o_bf     = (__hip_bfloat16*) alloc((size_t)M_ * E_ * 2);
  __hip_bfloat16*  mid_bf   = (__hip_bfloat16*) alloc((size_t)M_ * FF_ * 2);
  __hip_bfloat16*  whead_bt = (__hip_bfloat16*) alloc((size_t)VPAD_ * E_ * 2);
  bool preall = (off + (size_t)6 * WSLAB_ * 2 <= ws_size);
  __hip_bfloat16* wslab = (__hip_bfloat16*) alloc(((size_t)(preall ? 6 : 1)) * WSLAB_ * 2);

  dim3 blk(256);

  embed_kernel<<<(B_ * N_ * E_ + 255) / 256, blk, 0, stream>>>(x, tok, h);
  transpose_cast_kernel<<<dim3(E_ / 64, VPAD_ / 64), blk, 0, stream>>>(whead, whead_bt, E_, V_);
  if (preall)
    wtrans_kernel<<<6 * 1728, blk, 0, stream>>>(wq, wk, wv, wo, w1, w2, wslab, 0);

  dim3 gqkv(QKVW_ / 64, M_ / 128);    // 36x16 = 576 blocks
  dim3 gffn1(FF_ / 64, M_ / 128);     // 48x16 = 768 blocks
  dim3 gsm(E_ / 64, M_ / 64);         // BM=64: 12x32 = 384 blocks (wo, ffn2)
  dim3 gfa(N_ / 16, H_, B_);

  for (int l = 0; l < L_; ++l) {
    if (!preall)
      wtrans_kernel<<<1728, blk, 0, stream>>>(wq, wk, wv, wo, w1, w2, wslab, l);
    __hip_bfloat16* wb = wslab + (preall ? (size_t)l * WSLAB_ : 0);

    layernorm_kernel<<<M_, blk, 0, stream>>>(h, y_bf, ln1g + (size_t)l * E_, ln1b + (size_t)l * E_);
    gemm_bt_kernel<128><<<gqkv, blk, 0, stream>>>(y_bf, wb + OFF_QKV_, nullptr, nullptr,
        nullptr, qkv_bf, vt_bf, QKVW_, E_, 0);
    fattn_kernel<<<gfa, dim3(64), 0, stream>>>(qkv_bf, vt_bf, o_bf);
    gemm_bt_kernel<64><<<gsm, blk, 0, stream>>>(o_bf, wb + OFF_WO_, bo + (size_t)l * E_, h,
        h, nullptr, nullptr, E_, E_, 0);
    layernorm_kernel<<<M_, blk, 0, stream>>>(h, y_bf, ln2g + (size_t)l * E_, ln2b + (size_t)l * E_);
    gemm_bt_kernel<128><<<gffn1, blk, 0, stream>>>(y_bf, wb + OFF_W1_, b1 + (size_t)l * FF_,
        nullptr, nullptr, mid_bf, nullptr, FF_, E_, 1);
    gemm_bt_kernel<64><<<gsm, blk, 0, stream>>>(mid_bf, wb + OFF_W2_, b2 + (size_t)l * E_, h,
        h, nullptr, nullptr, E_, FF_, 0);
  }

  layernorm_kernel<<<M_, blk, 0, stream>>>(h, y_bf, lnfg, lnfb);
  // head: 128x128 tiles, BK=32 dbuf in 32KB, XCD-panel remap, fp32 nt epilogue
  head_gemm_kernel<<<dim3((VPAD_ / 128) * (M_ / 128)), blk, 0, stream>>>(
      y_bf, whead_bt, out, V_, E_, M_ / 128);
}